// Round 17
// baseline (438.650 us; speedup 1.0000x reference)
//
#include <hip/hip_runtime.h>
#include <cstdint>
#include <cstddef>

#define NN   50000
#define FIN  128
#define HD   128
#define EE   800000
#define C3   384   // 3*H
#define NOUT 40

#define SC_ELEMS 512
#define SC_BLKS  ((NN + SC_ELEMS - 1) / SC_ELEMS)   // 98
#define NBLK ((NN + 127) / 128)                     // 391 row-blocks

#define SPLIT_BLKS ((NN + 3) / 4)                   // 12500
#define HIST_BLKS  ((EE + 255) / 256)               // 3125

#define LDSW 132   // padded epilogue LDS row stride (ushorts)

typedef __attribute__((ext_vector_type(8))) short s8v;   // 8 x bf16 (4 VGPR)
typedef __attribute__((ext_vector_type(4))) float f4v;   // MFMA acc

typedef const __attribute__((address_space(1))) unsigned int* guintp;
typedef __attribute__((address_space(3))) unsigned int* luintp;

static __device__ __forceinline__ void async_copy16(const void* g, void* l) {
    __builtin_amdgcn_global_load_lds((guintp)g, (luintp)l, 16, 0, 0);
}

// ---------- bf16 helpers ----------
static __device__ __forceinline__ float b2f(ushort u) {
    return __uint_as_float((unsigned)u << 16);
}
static __device__ __forceinline__ ushort f2b(float v) {
    unsigned u = __float_as_uint(v);
    unsigned r = u + 0x7fffu + ((u >> 16) & 1u);
    return (ushort)(r >> 16);
}

// ---------- merged: x -> bf16, attention dots, AND dst-degree histogram ----------
__global__ __launch_bounds__(256) void k_split_x_att(
    const float* __restrict__ x,
    const float* __restrict__ w_as, const float* __restrict__ w_ad,
    const int* __restrict__ e_dst, int* __restrict__ degA,
    ushort* __restrict__ xb,
    float* __restrict__ a_s, float* __restrict__ a_d)
{
    if (blockIdx.x >= SPLIT_BLKS) {
        int gid = (blockIdx.x - SPLIT_BLKS) * 256 + threadIdx.x;
        if (gid < EE) atomicAdd(&degA[e_dst[gid]], 1);
        return;
    }
    int node = blockIdx.x * 4 + (threadIdx.x >> 6);
    if (node >= NN) return;
    int lane = threadIdx.x & 63;
    size_t o = (size_t)node * 128 + lane * 2;
    float2 v  = *(const float2*)(x + o);
    { ushort2 u; u.x = f2b(v.x); u.y = f2b(v.y); *(ushort2*)(xb + o) = u; }
    float2 w1 = *(const float2*)(w_as + lane * 2);
    float2 w2 = *(const float2*)(w_ad + lane * 2);
    float s1 = v.x * w1.x + v.y * w1.y;
    float s2 = v.x * w2.x + v.y * w2.y;
    #pragma unroll
    for (int off = 32; off; off >>= 1) {
        s1 += __shfl_down(s1, off);
        s2 += __shfl_down(s2, off);
    }
    if (lane == 0) { a_s[node] = s1; a_d[node] = s2; }
}

// ---------- weight transposes (single bf16 plane) + att fold ----------
__global__ void k_splitw_all(
    const float* __restrict__ Wg, const float* __restrict__ Wc,
    const float* __restrict__ Wl, const float* __restrict__ Wr,
    const float* __restrict__ W1, const float* __restrict__ W2,
    const float* __restrict__ W3,
    const float* __restrict__ asv, const float* __restrict__ adv,
    float* __restrict__ w_as, float* __restrict__ w_ad,
    ushort* __restrict__ btg, ushort* __restrict__ btc,
    ushort* __restrict__ btsg,
    ushort* __restrict__ bt1, ushort* __restrict__ bt2,
    ushort* __restrict__ bt3)
{
    int ry = blockIdx.x;
    int t = threadIdx.x;
    if (ry == 816) {
        if (t < 128) {
            float s1 = 0.f, s2 = 0.f;
            for (int j = 0; j < 128; ++j) {
                float w = Wg[t * 128 + j];
                s1 += w * asv[j];
                s2 += w * adv[j];
            }
            w_as[t] = s1; w_ad[t] = s2;
        }
        return;
    }
    const float* W = nullptr; ushort* dh; int K, Nw, n;
    bool sage = false;
    if (ry < 128)      { n = ry;       K = 128; Nw = 128; W = Wg; dh = btg; }
    else if (ry < 256) { n = ry - 128; K = 128; Nw = 128; W = Wc; dh = btc; }
    else if (ry < 384) { n = ry - 256; K = 256; Nw = 128; sage = true; dh = btsg; }
    else if (ry < 640) { n = ry - 384; K = 384; Nw = 256; W = W1; dh = bt1; }
    else if (ry < 768) { n = ry - 640; K = 256; Nw = 128; W = W2; dh = bt2; }
    else               { n = ry - 768; K = 128; Nw = 40;  W = W3; dh = bt3; }
    for (int k = t; k < K; k += 256) {
        float v;
        if (sage) v = (k < 128) ? Wl[(size_t)k * 128 + n] : Wr[(size_t)(k - 128) * 128 + n];
        else      v = (n < Nw) ? W[(size_t)k * Nw + n] : 0.f;
        dh[(size_t)n * K + k] = f2b(v);
    }
}

// ---------- MFMA GEMM: bf16 A and B, both DMA-staged via LDS ----------
// DOBN: apply relu(scale[k]*a + shift[k]) to A-frags after ds_read (fused BN).
// mode 0: relu(acc+bias) -> bf16 store; mode 2: acc+bias -> fp32, cols<colmax
template<int NT, int NCH, int AX, int DOBN>
__global__ __launch_bounds__(256, 5) void k_gemm2(
    const ushort* __restrict__ A, int K,
    const ushort* __restrict__ Bt,
    const float* __restrict__ scale, const float* __restrict__ shift,
    int M, int mode,
    const float* __restrict__ bias,
    float* __restrict__ Cf, int ldc,
    ushort* __restrict__ Ch, int ldch,
    int colmax)
{
    constexpr int COLS = NT * 16;
    constexpr int HOPU = 8 * COLS;       // B 16B-units per 64-k half (1 plane)
    constexpr int KTOT = NCH * 128;

    __shared__ __align__(16) ushort S[16384];   // 32 KB union
    ushort* Bs = S;
    ushort* As = S + 8192;

    const int lane = threadIdx.x & 63;
    const int wave = threadIdx.x >> 6;
    const int quad = lane >> 4;
    const int ln15 = lane & 15;
    const int brow = AX ? blockIdx.y : blockIdx.x;
    const int bcol = AX ? blockIdx.x : blockIdx.y;
    const int row0 = brow * 128 + wave * 32;
    const int col0 = bcol * COLS;
    const int Rbase = brow * 128;

    auto stageB = [&](int c, int h) {
        for (int u0 = wave * 64; u0 < HOPU; u0 += 256) {
            int u  = u0 + lane;
            int kq  = u / COLS;
            int col = u - kq * COLS;
            int kk  = c * 128 + h * 64 + kq * 8;
            const ushort* gp = Bt + (size_t)(col0 + col) * KTOT + kk;
            async_copy16(gp, (char*)Bs + (size_t)u0 * 16);
        }
    };
    auto stageA = [&](int c, int h) {
        #pragma unroll
        for (int i = 0; i < 4; ++i) {
            int u0 = (wave * 4 + i) * 64;
            int u  = u0 + lane;
            int row = u >> 3;
            int s   = u & 7;
            int sg  = s ^ (row & 7);
            int rr = Rbase + row; if (rr > M - 1) rr = M - 1;
            int kk = c * 128 + h * 64 + sg * 8;
            const ushort* gp = A + (size_t)rr * K + kk;
            async_copy16(gp, (char*)As + (size_t)u0 * 16);
        }
    };
    auto afrag = [&](int jj, int mt) -> s8v {
        int r = wave * 32 + mt * 16 + ln15;
        int sg = jj * 4 + quad;
        int unit = r * 8 + (sg ^ (r & 7));
        return *(const s8v*)(As + (size_t)unit * 8);
    };

    f4v acc[2][NT] = {};

    auto compute = [&](int jj, int kbase) {
        s8v a0 = afrag(jj, 0);
        s8v a1 = afrag(jj, 1);
        if (DOBN) {
            int kk = kbase + (jj * 4 + quad) * 8;
            #pragma unroll
            for (int i = 0; i < 8; i += 4) {
                float4 sc = *(const float4*)(scale + kk + i);
                float4 sh = *(const float4*)(shift + kk + i);
                float v;
                v = b2f((ushort)a0[i])     * sc.x + sh.x; a0[i]     = (short)f2b(v > 0.f ? v : 0.f);
                v = b2f((ushort)a0[i + 1]) * sc.y + sh.y; a0[i + 1] = (short)f2b(v > 0.f ? v : 0.f);
                v = b2f((ushort)a0[i + 2]) * sc.z + sh.z; a0[i + 2] = (short)f2b(v > 0.f ? v : 0.f);
                v = b2f((ushort)a0[i + 3]) * sc.w + sh.w; a0[i + 3] = (short)f2b(v > 0.f ? v : 0.f);
                v = b2f((ushort)a1[i])     * sc.x + sh.x; a1[i]     = (short)f2b(v > 0.f ? v : 0.f);
                v = b2f((ushort)a1[i + 1]) * sc.y + sh.y; a1[i + 1] = (short)f2b(v > 0.f ? v : 0.f);
                v = b2f((ushort)a1[i + 2]) * sc.z + sh.z; a1[i + 2] = (short)f2b(v > 0.f ? v : 0.f);
                v = b2f((ushort)a1[i + 3]) * sc.w + sh.w; a1[i + 3] = (short)f2b(v > 0.f ? v : 0.f);
            }
        }
        #pragma unroll
        for (int t = 0; t < NT; ++t) {
            int ub = (jj * 4 + quad) * COLS + t * 16 + ln15;
            s8v b = *(const s8v*)(Bs + (size_t)ub * 8);
            acc[0][t] = __builtin_amdgcn_mfma_f32_16x16x32_bf16(a0, b, acc[0][t], 0, 0, 0);
            acc[1][t] = __builtin_amdgcn_mfma_f32_16x16x32_bf16(a1, b, acc[1][t], 0, 0, 0);
        }
    };

    stageB(0, 0); stageA(0, 0);
    __syncthreads();

    #pragma unroll
    for (int ph = 0; ph < NCH; ++ph) {
        #pragma unroll
        for (int h = 0; h < 2; ++h) {
            int kbase = ph * 128 + h * 64;
            compute(0, kbase); compute(1, kbase);
            if (!(ph == NCH - 1 && h == 1)) {
                __syncthreads();
                int nc = ph, nh = h + 1;
                if (nh == 2) { nh = 0; ++nc; }
                stageB(nc, nh); stageA(nc, nh);
                __syncthreads();
            }
        }
    }

    if (NT == 8 && mode == 0) {
        __syncthreads();                          // staging LDS free now
        ushort* Lp = S + wave * 2176;             // wave-private quarter
        #pragma unroll
        for (int mt = 0; mt < 2; ++mt) {
            #pragma unroll
            for (int t = 0; t < NT; ++t) {
                int cc = col0 + t * 16 + ln15;
                #pragma unroll
                for (int r = 0; r < 4; ++r) {
                    float v = acc[mt][t][r] + bias[cc];
                    v = v > 0.f ? v : 0.f;
                    Lp[(quad * 4 + r) * LDSW + t * 16 + ln15] = f2b(v);
                }
            }
            int cb = (lane & 31) * 4;
            #pragma unroll
            for (int it = 0; it < 8; ++it) {
                int row2 = it * 2 + (lane >> 5);
                int rr = row0 + mt * 16 + row2;
                uint2 v = *(uint2*)(Lp + row2 * LDSW + cb);
                if (rr < M)
                    *(uint2*)(Ch + (size_t)rr * ldch + col0 + cb) = v;
            }
        }
    } else {
        #pragma unroll
        for (int t = 0; t < NT; ++t) {
            int cc = col0 + t * 16 + ln15;
            #pragma unroll
            for (int mt = 0; mt < 2; ++mt) {
                #pragma unroll
                for (int r = 0; r < 4; ++r) {
                    int rr = row0 + mt * 16 + quad * 4 + r;
                    if (rr < M && cc < colmax)
                        Cf[(size_t)rr * ldc + cc] = acc[mt][t][r] + bias[cc];
                }
            }
        }
    }
}

// ---------- merged producer GEMMs: z=0 GAT, z=1 GCN, z=2 SAGE ----------
// launch_bounds(256,3): keeps z0+z1 L2-resident hand-off (R14 lesson).
__global__ __launch_bounds__(256, 3) void k_gemm_prod(
    const ushort* __restrict__ tgb, const ushort* __restrict__ tcb,
    const ushort* __restrict__ tsb, const ushort* __restrict__ xb,
    const ushort* __restrict__ btg, const ushort* __restrict__ btc,
    const ushort* __restrict__ btsg,
    const float* __restrict__ bg, const float* __restrict__ bc,
    const float* __restrict__ bsl,
    float* __restrict__ pS, float* __restrict__ pQ,   // [NBLK][C3] partials
    ushort* __restrict__ hch)
{
    constexpr int COLS = 128;
    constexpr int HOPU = 8 * COLS;               // 1024 units per half
    __shared__ __align__(16) ushort S[16384];    // 32 KB union
    ushort* Bs = S;
    ushort* As = S + 8192;
    float* red = (float*)(S + 14336);            // 256 floats (dead As region)

    const int z = blockIdx.z;
    const ushort* A1 = (z == 0) ? tgb : (z == 1) ? tcb : tsb;
    const ushort* Bt = (z == 0) ? btg : (z == 1) ? btc : btsg;
    const float*  bias = (z == 0) ? bg : (z == 1) ? bc : bsl;
    const int nch = (z == 2) ? 2 : 1;
    const int ktot = nch * 128;

    const int lane = threadIdx.x & 63;
    const int wave = threadIdx.x >> 6;
    const int quad = lane >> 4;
    const int ln15 = lane & 15;
    const int row0 = blockIdx.x * 128 + wave * 32;
    const int Rbase = blockIdx.x * 128;

    auto stageB = [&](int c, int h) {
        for (int u0 = wave * 64; u0 < HOPU; u0 += 256) {
            int u  = u0 + lane;
            int kq  = u / COLS;
            int col = u - kq * COLS;
            int kk  = c * 128 + h * 64 + kq * 8;
            const ushort* gp = Bt + (size_t)col * ktot + kk;
            async_copy16(gp, (char*)Bs + (size_t)u0 * 16);
        }
    };
    auto stageA = [&](int c, int h) {
        #pragma unroll
        for (int i = 0; i < 4; ++i) {
            int u0 = (wave * 4 + i) * 64;
            int u  = u0 + lane;
            int row = u >> 3;
            int s   = u & 7;
            int sg  = s ^ (row & 7);
            int rr = Rbase + row; if (rr > NN - 1) rr = NN - 1;
            int kk = c * 128 + h * 64 + sg * 8;
            const ushort* gp = (kk < 128) ? (A1 + (size_t)rr * 128 + kk)
                                          : (xb + (size_t)rr * 128 + (kk - 128));
            async_copy16(gp, (char*)As + (size_t)u0 * 16);
        }
    };
    auto afrag = [&](int jj, int mt) -> s8v {
        int r = wave * 32 + mt * 16 + ln15;
        int sg = jj * 4 + quad;
        int unit = r * 8 + (sg ^ (r & 7));
        return *(const s8v*)(As + (size_t)unit * 8);
    };

    f4v acc[2][8] = {};

    auto compute = [&](int jj) {
        s8v a0 = afrag(jj, 0);
        s8v a1 = afrag(jj, 1);
        #pragma unroll
        for (int t = 0; t < 8; ++t) {
            int ub = (jj * 4 + quad) * COLS + t * 16 + ln15;
            s8v b = *(const s8v*)(Bs + (size_t)ub * 8);
            acc[0][t] = __builtin_amdgcn_mfma_f32_16x16x32_bf16(a0, b, acc[0][t], 0, 0, 0);
            acc[1][t] = __builtin_amdgcn_mfma_f32_16x16x32_bf16(a1, b, acc[1][t], 0, 0, 0);
        }
    };

    stageB(0, 0); stageA(0, 0);
    __syncthreads();

    for (int ph = 0; ph < nch; ++ph) {
        for (int h = 0; h < 2; ++h) {
            compute(0); compute(1);
            if (!(ph == nch - 1 && h == 1)) {
                __syncthreads();
                int nc = ph, nh = h + 1;
                if (nh == 2) { nh = 0; ++nc; }
                stageB(nc, nh); stageA(nc, nh);
                __syncthreads();
            }
        }
    }

    // LDS-transpose epilogue + per-lane BN partials
    __syncthreads();
    if (threadIdx.x < 256) red[threadIdx.x] = 0.f;   // As dead; red disjoint from Lp
    ushort* Lp = S + wave * 2176;
    float sp[8] = {}, qp[8] = {};
    #pragma unroll
    for (int mt = 0; mt < 2; ++mt) {
        #pragma unroll
        for (int t = 0; t < 8; ++t) {
            #pragma unroll
            for (int r = 0; r < 4; ++r) {
                int rr = row0 + mt * 16 + quad * 4 + r;
                float v = acc[mt][t][r] + bias[t * 16 + ln15];
                Lp[(quad * 4 + r) * LDSW + t * 16 + ln15] = f2b(v);
                if (rr < NN) { sp[t] += v; qp[t] += v * v; }
            }
        }
        int cb = (lane & 31) * 4;
        #pragma unroll
        for (int it = 0; it < 8; ++it) {
            int row2 = it * 2 + (lane >> 5);
            int rr = row0 + mt * 16 + row2;
            uint2 v = *(uint2*)(Lp + row2 * LDSW + cb);
            if (rr < NN)
                *(uint2*)(hch + (size_t)rr * C3 + z * 128 + cb) = v;
        }
    }
    // cross-wave LDS reduce (no contended global atomics)
    __syncthreads();
    #pragma unroll
    for (int t = 0; t < 8; ++t) {
        float s = sp[t], q = qp[t];
        s += __shfl_xor(s, 16); s += __shfl_xor(s, 32);
        q += __shfl_xor(q, 16); q += __shfl_xor(q, 32);
        if (quad == 0) {
            atomicAdd(&red[t * 16 + ln15], s);          // LDS atomic
            atomicAdd(&red[128 + t * 16 + ln15], q);
        }
    }
    __syncthreads();
    if (threadIdx.x < 128) {
        size_t o = (size_t)blockIdx.x * C3 + z * 128 + threadIdx.x;
        pS[o] = red[threadIdx.x];
        pQ[o] = red[128 + threadIdx.x];
    }
}

// ---------- hierarchical exclusive scan over (degA[i]+1) ----------
__global__ __launch_bounds__(256) void k_scan_part(
    const int* __restrict__ degA, int* __restrict__ bsum)
{
    int t = threadIdx.x;
    int b0 = blockIdx.x * SC_ELEMS;
    int i0 = b0 + t * 2;
    int v0 = (i0 < NN)     ? degA[i0] + 1     : 0;
    int v1 = (i0 + 1 < NN) ? degA[i0 + 1] + 1 : 0;
    int s = v0 + v1;
    #pragma unroll
    for (int off = 32; off; off >>= 1) s += __shfl_down(s, off);
    __shared__ int ws[4];
    if ((t & 63) == 0) ws[t >> 6] = s;
    __syncthreads();
    if (t == 0) bsum[blockIdx.x] = ws[0] + ws[1] + ws[2] + ws[3];
}

__global__ __launch_bounds__(128) void k_scan_tops(
    const int* __restrict__ bsum, int* __restrict__ boffs)
{
    __shared__ int sh[128];
    int t = threadIdx.x;
    int v = (t < SC_BLKS) ? bsum[t] : 0;
    sh[t] = v;
    __syncthreads();
    for (int off = 1; off < 128; off <<= 1) {
        int u = (t >= off) ? sh[t - off] : 0;
        __syncthreads();
        sh[t] += u;
        __syncthreads();
    }
    if (t < SC_BLKS) boffs[t] = sh[t] - v;   // exclusive
    if (t == SC_BLKS - 1) boffs[SC_BLKS] = sh[t];
}

__global__ __launch_bounds__(256) void k_scan_apply(
    const int* __restrict__ degA, const int* __restrict__ boffs,
    int* __restrict__ offs, int* __restrict__ cursor,
    float* __restrict__ dinv)
{
    __shared__ int sh[256];
    int t = threadIdx.x;
    int b0 = blockIdx.x * SC_ELEMS;
    int i0 = b0 + t * 2;
    int v0 = (i0 < NN)     ? degA[i0] + 1     : 0;
    int v1 = (i0 + 1 < NN) ? degA[i0 + 1] + 1 : 0;
    int pair = v0 + v1;
    sh[t] = pair;
    __syncthreads();
    for (int off = 1; off < 256; off <<= 1) {
        int u = (t >= off) ? sh[t - off] : 0;
        __syncthreads();
        sh[t] += u;
        __syncthreads();
    }
    int excl = sh[t] - pair + boffs[blockIdx.x];
    if (i0 < NN) {
        offs[i0] = excl; cursor[i0] = excl;
        dinv[i0] = rsqrtf((float)v0);
    }
    if (i0 + 1 < NN) {
        offs[i0 + 1] = excl + v0; cursor[i0 + 1] = excl + v0;
        dinv[i0 + 1] = rsqrtf((float)v1);
    }
    if (blockIdx.x == SC_BLKS - 1 && t == 255) offs[NN] = excl + pair;
}

// ---------- CSR fill: store SRC directly (self-slots store d) ----------
__global__ void k_csr_fill(const int* __restrict__ src, const int* __restrict__ dst,
                           int* __restrict__ cursor, int* __restrict__ esrc)
{
    int gid = blockIdx.x * blockDim.x + threadIdx.x;
    if (gid >= EE + NN) return;
    int d, s;
    if (gid < EE) { d = dst[gid]; s = src[gid]; }
    else          { d = gid - EE; s = d; }
    int slot = atomicAdd(&cursor[d], 1);
    esrc[slot] = s;
}

// ---------- CSR gather with in-wave softmax; src stored in-slot ----------
__global__ __launch_bounds__(256) void k_gather(
    const int* __restrict__ esrc, const int* __restrict__ offs,
    const float* __restrict__ a_s, const float* __restrict__ a_d,
    const float* __restrict__ dinv,
    const ushort* __restrict__ xb,
    ushort* __restrict__ tgb, ushort* __restrict__ tcb,
    ushort* __restrict__ tsb)
{
    int d = blockIdx.x * 4 + (threadIdx.x >> 6);
    if (d >= NN) return;
    int lane = threadIdx.x & 63;
    int beg = offs[d], end = offs[d + 1];
    float ad = a_d[d], dd = dinv[d];

    int idx0 = beg + lane;
    bool v0 = idx0 < end;
    int s0 = d; float e0 = 0.f, wc0 = 0.f;
    if (v0) {
        s0 = esrc[idx0];
        float e = a_s[s0] + ad;
        e0 = (e > 0.f) ? e : 0.2f * e;
        wc0 = dinv[s0] * dd;
    }
    float m = v0 ? e0 : -3.0e38f;
    for (int base = beg + 64; base < end; base += 64) {
        int idx = base + lane;
        if (idx < end) {
            int s = esrc[idx];
            float e = a_s[s] + ad;
            e = (e > 0.f) ? e : 0.2f * e;
            m = fmaxf(m, e);
        }
    }
    #pragma unroll
    for (int off = 1; off < 64; off <<= 1) m = fmaxf(m, __shfl_xor(m, off));
    float ex0 = v0 ? expf(e0 - m) : 0.f;
    float den = ex0;
    for (int base = beg + 64; base < end; base += 64) {
        int idx = base + lane;
        if (idx < end) {
            int s = esrc[idx];
            float e = a_s[s] + ad;
            e = (e > 0.f) ? e : 0.2f * e;
            den += expf(e - m);
        }
    }
    #pragma unroll
    for (int off = 1; off < 64; off <<= 1) den += __shfl_xor(den, off);
    float rden = 1.f / den;

    float2 tg = {0.f, 0.f}, tc = {0.f, 0.f}, ts = {0.f, 0.f};
    int c = lane * 2;
    {
        float wg = ex0 * rden;      // 0 when invalid (ex0 = 0)
        float wc = wc0;
        int cnt = end - beg; if (cnt > 64) cnt = 64;
        for (int j = 0; j < cnt; ++j) {
            int   sj  = __shfl(s0, j);
            float wgj = __shfl(wg, j);
            float wcj = __shfl(wc, j);
            ushort2 xu = *(const ushort2*)(xb + (size_t)sj * 128 + c);
            float xvx = b2f(xu.x), xvy = b2f(xu.y);
            tg.x += wgj * xvx; tg.y += wgj * xvy;
            tc.x += wcj * xvx; tc.y += wcj * xvy;
            ts.x += xvx;       ts.y += xvy;
        }
    }
    for (int base = beg + 64; base < end; base += 64) {
        int idx = base + lane;
        int s = d; float wg = 0.f, wc = 0.f;
        if (idx < end) {
            s = esrc[idx];
            float e = a_s[s] + ad;
            e = (e > 0.f) ? e : 0.2f * e;
            wg = expf(e - m) * rden;
            wc = dinv[s] * dd;
        }
        int cnt = end - base; if (cnt > 64) cnt = 64;
        for (int j = 0; j < cnt; ++j) {
            int   sj  = __shfl(s, j);
            float wgj = __shfl(wg, j);
            float wcj = __shfl(wc, j);
            ushort2 xu = *(const ushort2*)(xb + (size_t)sj * 128 + c);
            float xvx = b2f(xu.x), xvy = b2f(xu.y);
            tg.x += wgj * xvx; tg.y += wgj * xvy;
            tc.x += wcj * xvx; tc.y += wcj * xvy;
            ts.x += xvx;       ts.y += xvy;
        }
    }
    ushort2 xdu = *(const ushort2*)(xb + (size_t)d * 128 + c);
    ts.x -= b2f(xdu.x); ts.y -= b2f(xdu.y);
    int cs = (end - beg) - 1;
    float rc = 1.f / (float)(cs > 1 ? cs : 1);
    ts.x *= rc; ts.y *= rc;

    size_t row = (size_t)d * 128 + c;
    { ushort2 u; u.x = f2b(tg.x); u.y = f2b(tg.y); *(ushort2*)(tgb + row) = u; }
    { ushort2 u; u.x = f2b(tc.x); u.y = f2b(tc.y); *(ushort2*)(tcb + row) = u; }
    { ushort2 u; u.x = f2b(ts.x); u.y = f2b(ts.y); *(ushort2*)(tsb + row) = u; }
}

// ---------- BN final: reduce per-block partials, fold gamma/beta ----------
__global__ void k_bn_final(const float* __restrict__ pS, const float* __restrict__ pQ,
                           const float* __restrict__ gamma, const float* __restrict__ beta,
                           float* __restrict__ scale, float* __restrict__ shift)
{
    int j = threadIdx.x;
    if (j >= C3) return;
    float s = 0.f, q = 0.f;
    for (int r = 0; r < NBLK; ++r) {
        s += pS[(size_t)r * C3 + j];
        q += pQ[(size_t)r * C3 + j];
    }
    const float rn = 1.f / (float)NN;
    float mu  = s * rn;
    float var = q * rn - mu * mu;
    float sc  = gamma[j] * rsqrtf(var + 1e-5f);
    scale[j] = sc;
    shift[j] = beta[j] - mu * sc;
}

extern "C" void kernel_launch(void* const* d_in, const int* in_sizes, int n_in,
                              void* d_out, int out_size, void* d_ws, size_t ws_size,
                              hipStream_t stream) {
    const float* x        = (const float*)d_in[0];
    const int*   ei       = (const int*)d_in[1];
    const float* W_gat    = (const float*)d_in[2];
    const float* att_src  = (const float*)d_in[3];
    const float* att_dst  = (const float*)d_in[4];
    const float* b_gat    = (const float*)d_in[5];
    const float* W_gcn    = (const float*)d_in[6];
    const float* b_gcn    = (const float*)d_in[7];
    const float* W_sage_l = (const float*)d_in[8];
    const float* b_sage_l = (const float*)d_in[9];
    const float* W_sage_r = (const float*)d_in[10];
    const float* W1       = (const float*)d_in[11];
    const float* b1       = (const float*)d_in[12];
    const float* W2       = (const float*)d_in[13];
    const float* b2       = (const float*)d_in[14];
    const float* W3       = (const float*)d_in[15];
    const float* b3       = (const float*)d_in[16];
    const float* gamma    = (const float*)d_in[17];
    const float* beta     = (const float*)d_in[18];

    const int* e_src = ei;
    const int* e_dst = ei + EE;

    // ---- workspace layout (16B-aligned) ----
    char* base = (char*)d_ws;
    size_t o = 0;
    ushort* hch  = (ushort*)(base + o); o += (size_t)NN * C3 * 2;
    ushort* tgb  = (ushort*)(base + o); o += (size_t)NN * 128 * 2;    // a1 overlay
    ushort* tcb  = (ushort*)(base + o); o += (size_t)NN * 128 * 2;
    ushort* tsb  = (ushort*)(base + o); o += (size_t)NN * 128 * 2;    // a2 overlay
    ushort* xb   = (ushort*)(base + o); o += (size_t)NN * 128 * 2;
    int*    esrc = (int*)(base + o);    o += (size_t)(EE + NN) * 4;
    int*    offs = (int*)(base + o);    o += (size_t)(NN + 16) * 4;
    int*    cursor=(int*)(base + o);    o += (size_t)NN * 4;
    float*  as_  = (float*)(base + o);  o += (size_t)NN * 4;
    float*  ad_  = (float*)(base + o);  o += (size_t)NN * 4;
    float*  dinv = (float*)(base + o);  o += (size_t)NN * 4;
    int*    bsum = (int*)(base + o);    o += 256 * 4;
    int*    boffs= (int*)(base + o);    o += 256 * 4;
    // --- zero-init region: degA only ---
    int*    degA = (int*)(base + o);    o += (size_t)NN * 4;
    // --- end zero region ---
    float*  pS   = (float*)(base + o);  o += (size_t)NBLK * C3 * 4;   // written fully
    float*  pQ   = (float*)(base + o);  o += (size_t)NBLK * C3 * 4;
    float*  scale= (float*)(base + o);  o += C3 * 4;
    float*  shift= (float*)(base + o);  o += C3 * 4;
    float*  w_as = (float*)(base + o);  o += 128 * 4;
    float*  w_ad = (float*)(base + o);  o += 128 * 4;
    ushort* btg  = (ushort*)(base + o); o += 128 * 128 * 2;
    ushort* btc  = (ushort*)(base + o); o += 128 * 128 * 2;
    ushort* btsg = (ushort*)(base + o); o += 128 * 256 * 2;
    ushort* bt1  = (ushort*)(base + o); o += 256 * 384 * 2;
    ushort* bt2  = (ushort*)(base + o); o += 128 * 256 * 2;
    ushort* bt3  = (ushort*)(base + o); o += 48 * 128 * 2;
    // overlays (temporally disjoint)
    ushort* a1 = tgb;                        // NN*256 ushorts (tgb+tcb)
    ushort* a2 = tsb;                        // NN*128

    hipMemsetAsync(degA, 0, (size_t)NN * 4, stream);

    // ---- weight prep ----
    k_splitw_all<<<817, 256, 0, stream>>>(W_gat, W_gcn, W_sage_l, W_sage_r, W1, W2, W3,
        att_src, att_dst, w_as, w_ad, btg, btc, btsg, bt1, bt2, bt3);
    // split x + attention dots + degree histogram (merged)
    k_split_x_att<<<SPLIT_BLKS + HIST_BLKS, 256, 0, stream>>>(
        x, w_as, w_ad, e_dst, degA, xb, as_, ad_);

    // ---- CSR build ----
    k_scan_part<<<SC_BLKS, 256, 0, stream>>>(degA, bsum);
    k_scan_tops<<<1, 128, 0, stream>>>(bsum, boffs);
    k_scan_apply<<<SC_BLKS, 256, 0, stream>>>(degA, boffs, offs, cursor, dinv);
    k_csr_fill<<<(EE + NN + 255) / 256, 256, 0, stream>>>(e_src, e_dst, cursor, esrc);

    // ---- gather (bf16 x, direct-src CSR) ----
    k_gather<<<(NN + 3) / 4, 256, 0, stream>>>(
        esrc, offs, as_, ad_, dinv, xb, tgb, tcb, tsb);

    // ---- producers: one launch, privatized BN partials ----
    k_gemm_prod<<<dim3(NBLK, 1, 3), 256, 0, stream>>>(
        tgb, tcb, tsb, xb, btg, btc, btsg,
        b_gat, b_gcn, b_sage_l, pS, pQ, hch);

    // ---- BN fold (partials reduce) ----
    k_bn_final<<<1, C3, 0, stream>>>(pS, pQ, gamma, beta, scale, shift);

    // ---- MLP (MLP1 applies BN+relu to A-frags in-kernel; k_bnrelu deleted) ----
    k_gemm2<8, 3, 1, 1><<<dim3(2, NBLK), 256, 0, stream>>>(
        hch, 384, bt1, scale, shift, NN, 0, b1, nullptr, 0, a1, 256, 256);
    k_gemm2<8, 2, 0, 0><<<dim3(NBLK, 1), 256, 0, stream>>>(
        a1, 256, bt2, nullptr, nullptr, NN, 0, b2, nullptr, 0, a2, 128, 128);
    k_gemm2<3, 1, 0, 0><<<dim3(NBLK, 1), 256, 0, stream>>>(
        a2, 128, bt3, nullptr, nullptr, NN, 2, b3, (float*)d_out, NOUT, nullptr, 0, NOUT);
}

// Round 18
// 421.565 us; speedup vs baseline: 1.0405x; 1.0405x over previous
//
#include <hip/hip_runtime.h>
#include <cstdint>
#include <cstddef>

#define NN   50000
#define FIN  128
#define HD   128
#define EE   800000
#define C3   384   // 3*H
#define NOUT 40

#define SC_ELEMS 512
#define SC_BLKS  ((NN + SC_ELEMS - 1) / SC_ELEMS)   // 98
#define NBLK ((NN + 127) / 128)                     // 391 row-blocks

#define SPLIT_BLKS ((NN + 3) / 4)                   // 12500
#define HIST_BLKS  ((EE + 255) / 256)               // 3125

#define LDSW 132   // padded epilogue LDS row stride (ushorts)

typedef __attribute__((ext_vector_type(8))) short s8v;   // 8 x bf16 (4 VGPR)
typedef __attribute__((ext_vector_type(4))) float f4v;   // MFMA acc

typedef const __attribute__((address_space(1))) unsigned int* guintp;
typedef __attribute__((address_space(3))) unsigned int* luintp;

static __device__ __forceinline__ void async_copy16(const void* g, void* l) {
    __builtin_amdgcn_global_load_lds((guintp)g, (luintp)l, 16, 0, 0);
}

// ---------- bf16 helpers ----------
static __device__ __forceinline__ float b2f(ushort u) {
    return __uint_as_float((unsigned)u << 16);
}
static __device__ __forceinline__ ushort f2b(float v) {
    unsigned u = __float_as_uint(v);
    unsigned r = u + 0x7fffu + ((u >> 16) & 1u);
    return (ushort)(r >> 16);
}

// ---------- merged: x -> bf16, attention dots, AND dst-degree histogram ----------
__global__ __launch_bounds__(256) void k_split_x_att(
    const float* __restrict__ x,
    const float* __restrict__ w_as, const float* __restrict__ w_ad,
    const int* __restrict__ e_dst, int* __restrict__ degA,
    ushort* __restrict__ xb,
    float* __restrict__ a_s, float* __restrict__ a_d)
{
    if (blockIdx.x >= SPLIT_BLKS) {
        int gid = (blockIdx.x - SPLIT_BLKS) * 256 + threadIdx.x;
        if (gid < EE) atomicAdd(&degA[e_dst[gid]], 1);
        return;
    }
    int node = blockIdx.x * 4 + (threadIdx.x >> 6);
    if (node >= NN) return;
    int lane = threadIdx.x & 63;
    size_t o = (size_t)node * 128 + lane * 2;
    float2 v  = *(const float2*)(x + o);
    { ushort2 u; u.x = f2b(v.x); u.y = f2b(v.y); *(ushort2*)(xb + o) = u; }
    float2 w1 = *(const float2*)(w_as + lane * 2);
    float2 w2 = *(const float2*)(w_ad + lane * 2);
    float s1 = v.x * w1.x + v.y * w1.y;
    float s2 = v.x * w2.x + v.y * w2.y;
    #pragma unroll
    for (int off = 32; off; off >>= 1) {
        s1 += __shfl_down(s1, off);
        s2 += __shfl_down(s2, off);
    }
    if (lane == 0) { a_s[node] = s1; a_d[node] = s2; }
}

// ---------- weight transposes (single bf16 plane) + att fold ----------
__global__ void k_splitw_all(
    const float* __restrict__ Wg, const float* __restrict__ Wc,
    const float* __restrict__ Wl, const float* __restrict__ Wr,
    const float* __restrict__ W1, const float* __restrict__ W2,
    const float* __restrict__ W3,
    const float* __restrict__ asv, const float* __restrict__ adv,
    float* __restrict__ w_as, float* __restrict__ w_ad,
    ushort* __restrict__ btg, ushort* __restrict__ btc,
    ushort* __restrict__ btsg,
    ushort* __restrict__ bt1, ushort* __restrict__ bt2,
    ushort* __restrict__ bt3)
{
    int ry = blockIdx.x;
    int t = threadIdx.x;
    if (ry == 816) {
        if (t < 128) {
            float s1 = 0.f, s2 = 0.f;
            for (int j = 0; j < 128; ++j) {
                float w = Wg[t * 128 + j];
                s1 += w * asv[j];
                s2 += w * adv[j];
            }
            w_as[t] = s1; w_ad[t] = s2;
        }
        return;
    }
    const float* W = nullptr; ushort* dh; int K, Nw, n;
    bool sage = false;
    if (ry < 128)      { n = ry;       K = 128; Nw = 128; W = Wg; dh = btg; }
    else if (ry < 256) { n = ry - 128; K = 128; Nw = 128; W = Wc; dh = btc; }
    else if (ry < 384) { n = ry - 256; K = 256; Nw = 128; sage = true; dh = btsg; }
    else if (ry < 640) { n = ry - 384; K = 384; Nw = 256; W = W1; dh = bt1; }
    else if (ry < 768) { n = ry - 640; K = 256; Nw = 128; W = W2; dh = bt2; }
    else               { n = ry - 768; K = 128; Nw = 40;  W = W3; dh = bt3; }
    for (int k = t; k < K; k += 256) {
        float v;
        if (sage) v = (k < 128) ? Wl[(size_t)k * 128 + n] : Wr[(size_t)(k - 128) * 128 + n];
        else      v = (n < Nw) ? W[(size_t)k * Nw + n] : 0.f;
        dh[(size_t)n * K + k] = f2b(v);
    }
}

// ---------- MFMA GEMM: bf16 A and B, both DMA-staged via LDS ----------
// mode 0: relu(acc+bias) -> bf16 store; mode 2: acc+bias -> fp32, cols<colmax
template<int NT, int NCH, int AX>
__global__ __launch_bounds__(256, 5) void k_gemm2(
    const ushort* __restrict__ A, int K,
    const ushort* __restrict__ Bt,
    int M, int mode,
    const float* __restrict__ bias,
    float* __restrict__ Cf, int ldc,
    ushort* __restrict__ Ch, int ldch,
    int colmax)
{
    constexpr int COLS = NT * 16;
    constexpr int HOPU = 8 * COLS;       // B 16B-units per 64-k half (1 plane)
    constexpr int KTOT = NCH * 128;

    __shared__ __align__(16) ushort S[16384];   // 32 KB union
    ushort* Bs = S;
    ushort* As = S + 8192;

    const int lane = threadIdx.x & 63;
    const int wave = threadIdx.x >> 6;
    const int quad = lane >> 4;
    const int ln15 = lane & 15;
    const int brow = AX ? blockIdx.y : blockIdx.x;
    const int bcol = AX ? blockIdx.x : blockIdx.y;
    const int row0 = brow * 128 + wave * 32;
    const int col0 = bcol * COLS;
    const int Rbase = brow * 128;

    auto stageB = [&](int c, int h) {
        for (int u0 = wave * 64; u0 < HOPU; u0 += 256) {
            int u  = u0 + lane;
            int kq  = u / COLS;
            int col = u - kq * COLS;
            int kk  = c * 128 + h * 64 + kq * 8;
            const ushort* gp = Bt + (size_t)(col0 + col) * KTOT + kk;
            async_copy16(gp, (char*)Bs + (size_t)u0 * 16);
        }
    };
    auto stageA = [&](int c, int h) {
        #pragma unroll
        for (int i = 0; i < 4; ++i) {
            int u0 = (wave * 4 + i) * 64;
            int u  = u0 + lane;
            int row = u >> 3;
            int s   = u & 7;
            int sg  = s ^ (row & 7);
            int rr = Rbase + row; if (rr > M - 1) rr = M - 1;
            int kk = c * 128 + h * 64 + sg * 8;
            const ushort* gp = A + (size_t)rr * K + kk;
            async_copy16(gp, (char*)As + (size_t)u0 * 16);
        }
    };
    auto afrag = [&](int jj, int mt) -> s8v {
        int r = wave * 32 + mt * 16 + ln15;
        int sg = jj * 4 + quad;
        int unit = r * 8 + (sg ^ (r & 7));
        return *(const s8v*)(As + (size_t)unit * 8);
    };

    f4v acc[2][NT] = {};

    auto compute = [&](int jj) {
        s8v a0 = afrag(jj, 0);
        s8v a1 = afrag(jj, 1);
        #pragma unroll
        for (int t = 0; t < NT; ++t) {
            int ub = (jj * 4 + quad) * COLS + t * 16 + ln15;
            s8v b = *(const s8v*)(Bs + (size_t)ub * 8);
            acc[0][t] = __builtin_amdgcn_mfma_f32_16x16x32_bf16(a0, b, acc[0][t], 0, 0, 0);
            acc[1][t] = __builtin_amdgcn_mfma_f32_16x16x32_bf16(a1, b, acc[1][t], 0, 0, 0);
        }
    };

    stageB(0, 0); stageA(0, 0);
    __syncthreads();

    #pragma unroll
    for (int ph = 0; ph < NCH; ++ph) {
        #pragma unroll
        for (int h = 0; h < 2; ++h) {
            compute(0); compute(1);
            if (!(ph == NCH - 1 && h == 1)) {
                __syncthreads();
                int nc = ph, nh = h + 1;
                if (nh == 2) { nh = 0; ++nc; }
                stageB(nc, nh); stageA(nc, nh);
                __syncthreads();
            }
        }
    }

    if (NT == 8 && mode == 0) {
        __syncthreads();                          // staging LDS free now
        ushort* Lp = S + wave * 2176;             // wave-private quarter
        #pragma unroll
        for (int mt = 0; mt < 2; ++mt) {
            #pragma unroll
            for (int t = 0; t < NT; ++t) {
                int cc = col0 + t * 16 + ln15;
                #pragma unroll
                for (int r = 0; r < 4; ++r) {
                    float v = acc[mt][t][r] + bias[cc];
                    v = v > 0.f ? v : 0.f;
                    Lp[(quad * 4 + r) * LDSW + t * 16 + ln15] = f2b(v);
                }
            }
            int cb = (lane & 31) * 4;
            #pragma unroll
            for (int it = 0; it < 8; ++it) {
                int row2 = it * 2 + (lane >> 5);
                int rr = row0 + mt * 16 + row2;
                uint2 v = *(uint2*)(Lp + row2 * LDSW + cb);
                if (rr < M)
                    *(uint2*)(Ch + (size_t)rr * ldch + col0 + cb) = v;
            }
        }
    } else {
        #pragma unroll
        for (int t = 0; t < NT; ++t) {
            int cc = col0 + t * 16 + ln15;
            #pragma unroll
            for (int mt = 0; mt < 2; ++mt) {
                #pragma unroll
                for (int r = 0; r < 4; ++r) {
                    int rr = row0 + mt * 16 + quad * 4 + r;
                    if (rr < M && cc < colmax)
                        Cf[(size_t)rr * ldc + cc] = acc[mt][t][r] + bias[cc];
                }
            }
        }
    }
}

// ---------- merged producer GEMMs: z=0 GAT, z=1 GCN, z=2 SAGE ----------
// launch_bounds(256,3): keeps z0+z1 L2-resident hand-off (R14 lesson).
__global__ __launch_bounds__(256, 3) void k_gemm_prod(
    const ushort* __restrict__ tgb, const ushort* __restrict__ tcb,
    const ushort* __restrict__ tsb, const ushort* __restrict__ xb,
    const ushort* __restrict__ btg, const ushort* __restrict__ btc,
    const ushort* __restrict__ btsg,
    const float* __restrict__ bg, const float* __restrict__ bc,
    const float* __restrict__ bsl,
    float* __restrict__ pS, float* __restrict__ pQ,   // [NBLK][C3] partials
    ushort* __restrict__ hch)
{
    constexpr int COLS = 128;
    constexpr int HOPU = 8 * COLS;               // 1024 units per half
    __shared__ __align__(16) ushort S[16384];    // 32 KB union
    ushort* Bs = S;
    ushort* As = S + 8192;
    float* red = (float*)(S + 14336);            // 256 floats (dead As region)

    const int z = blockIdx.z;
    const ushort* A1 = (z == 0) ? tgb : (z == 1) ? tcb : tsb;
    const ushort* Bt = (z == 0) ? btg : (z == 1) ? btc : btsg;
    const float*  bias = (z == 0) ? bg : (z == 1) ? bc : bsl;
    const int nch = (z == 2) ? 2 : 1;
    const int ktot = nch * 128;

    const int lane = threadIdx.x & 63;
    const int wave = threadIdx.x >> 6;
    const int quad = lane >> 4;
    const int ln15 = lane & 15;
    const int row0 = blockIdx.x * 128 + wave * 32;
    const int Rbase = blockIdx.x * 128;

    auto stageB = [&](int c, int h) {
        for (int u0 = wave * 64; u0 < HOPU; u0 += 256) {
            int u  = u0 + lane;
            int kq  = u / COLS;
            int col = u - kq * COLS;
            int kk  = c * 128 + h * 64 + kq * 8;
            const ushort* gp = Bt + (size_t)col * ktot + kk;
            async_copy16(gp, (char*)Bs + (size_t)u0 * 16);
        }
    };
    auto stageA = [&](int c, int h) {
        #pragma unroll
        for (int i = 0; i < 4; ++i) {
            int u0 = (wave * 4 + i) * 64;
            int u  = u0 + lane;
            int row = u >> 3;
            int s   = u & 7;
            int sg  = s ^ (row & 7);
            int rr = Rbase + row; if (rr > NN - 1) rr = NN - 1;
            int kk = c * 128 + h * 64 + sg * 8;
            const ushort* gp = (kk < 128) ? (A1 + (size_t)rr * 128 + kk)
                                          : (xb + (size_t)rr * 128 + (kk - 128));
            async_copy16(gp, (char*)As + (size_t)u0 * 16);
        }
    };
    auto afrag = [&](int jj, int mt) -> s8v {
        int r = wave * 32 + mt * 16 + ln15;
        int sg = jj * 4 + quad;
        int unit = r * 8 + (sg ^ (r & 7));
        return *(const s8v*)(As + (size_t)unit * 8);
    };

    f4v acc[2][8] = {};

    auto compute = [&](int jj) {
        s8v a0 = afrag(jj, 0);
        s8v a1 = afrag(jj, 1);
        #pragma unroll
        for (int t = 0; t < 8; ++t) {
            int ub = (jj * 4 + quad) * COLS + t * 16 + ln15;
            s8v b = *(const s8v*)(Bs + (size_t)ub * 8);
            acc[0][t] = __builtin_amdgcn_mfma_f32_16x16x32_bf16(a0, b, acc[0][t], 0, 0, 0);
            acc[1][t] = __builtin_amdgcn_mfma_f32_16x16x32_bf16(a1, b, acc[1][t], 0, 0, 0);
        }
    };

    stageB(0, 0); stageA(0, 0);
    __syncthreads();

    for (int ph = 0; ph < nch; ++ph) {
        for (int h = 0; h < 2; ++h) {
            compute(0); compute(1);
            if (!(ph == nch - 1 && h == 1)) {
                __syncthreads();
                int nc = ph, nh = h + 1;
                if (nh == 2) { nh = 0; ++nc; }
                stageB(nc, nh); stageA(nc, nh);
                __syncthreads();
            }
        }
    }

    // LDS-transpose epilogue + per-lane BN partials
    __syncthreads();
    if (threadIdx.x < 256) red[threadIdx.x] = 0.f;   // As dead; red disjoint from Lp
    ushort* Lp = S + wave * 2176;
    float sp[8] = {}, qp[8] = {};
    #pragma unroll
    for (int mt = 0; mt < 2; ++mt) {
        #pragma unroll
        for (int t = 0; t < 8; ++t) {
            #pragma unroll
            for (int r = 0; r < 4; ++r) {
                int rr = row0 + mt * 16 + quad * 4 + r;
                float v = acc[mt][t][r] + bias[t * 16 + ln15];
                Lp[(quad * 4 + r) * LDSW + t * 16 + ln15] = f2b(v);
                if (rr < NN) { sp[t] += v; qp[t] += v * v; }
            }
        }
        int cb = (lane & 31) * 4;
        #pragma unroll
        for (int it = 0; it < 8; ++it) {
            int row2 = it * 2 + (lane >> 5);
            int rr = row0 + mt * 16 + row2;
            uint2 v = *(uint2*)(Lp + row2 * LDSW + cb);
            if (rr < NN)
                *(uint2*)(hch + (size_t)rr * C3 + z * 128 + cb) = v;
        }
    }
    // cross-wave LDS reduce (no contended global atomics)
    __syncthreads();
    #pragma unroll
    for (int t = 0; t < 8; ++t) {
        float s = sp[t], q = qp[t];
        s += __shfl_xor(s, 16); s += __shfl_xor(s, 32);
        q += __shfl_xor(q, 16); q += __shfl_xor(q, 32);
        if (quad == 0) {
            atomicAdd(&red[t * 16 + ln15], s);          // LDS atomic
            atomicAdd(&red[128 + t * 16 + ln15], q);
        }
    }
    __syncthreads();
    if (threadIdx.x < 128) {
        size_t o = (size_t)blockIdx.x * C3 + z * 128 + threadIdx.x;
        pS[o] = red[threadIdx.x];
        pQ[o] = red[128 + threadIdx.x];
    }
}

// ---------- hierarchical exclusive scan over (degA[i]+1) ----------
__global__ __launch_bounds__(256) void k_scan_part(
    const int* __restrict__ degA, int* __restrict__ bsum)
{
    int t = threadIdx.x;
    int b0 = blockIdx.x * SC_ELEMS;
    int i0 = b0 + t * 2;
    int v0 = (i0 < NN)     ? degA[i0] + 1     : 0;
    int v1 = (i0 + 1 < NN) ? degA[i0 + 1] + 1 : 0;
    int s = v0 + v1;
    #pragma unroll
    for (int off = 32; off; off >>= 1) s += __shfl_down(s, off);
    __shared__ int ws[4];
    if ((t & 63) == 0) ws[t >> 6] = s;
    __syncthreads();
    if (t == 0) bsum[blockIdx.x] = ws[0] + ws[1] + ws[2] + ws[3];
}

__global__ __launch_bounds__(128) void k_scan_tops(
    const int* __restrict__ bsum, int* __restrict__ boffs)
{
    __shared__ int sh[128];
    int t = threadIdx.x;
    int v = (t < SC_BLKS) ? bsum[t] : 0;
    sh[t] = v;
    __syncthreads();
    for (int off = 1; off < 128; off <<= 1) {
        int u = (t >= off) ? sh[t - off] : 0;
        __syncthreads();
        sh[t] += u;
        __syncthreads();
    }
    if (t < SC_BLKS) boffs[t] = sh[t] - v;   // exclusive
    if (t == SC_BLKS - 1) boffs[SC_BLKS] = sh[t];
}

__global__ __launch_bounds__(256) void k_scan_apply(
    const int* __restrict__ degA, const int* __restrict__ boffs,
    int* __restrict__ offs, int* __restrict__ cursor,
    float* __restrict__ dinv)
{
    __shared__ int sh[256];
    int t = threadIdx.x;
    int b0 = blockIdx.x * SC_ELEMS;
    int i0 = b0 + t * 2;
    int v0 = (i0 < NN)     ? degA[i0] + 1     : 0;
    int v1 = (i0 + 1 < NN) ? degA[i0 + 1] + 1 : 0;
    int pair = v0 + v1;
    sh[t] = pair;
    __syncthreads();
    for (int off = 1; off < 256; off <<= 1) {
        int u = (t >= off) ? sh[t - off] : 0;
        __syncthreads();
        sh[t] += u;
        __syncthreads();
    }
    int excl = sh[t] - pair + boffs[blockIdx.x];
    if (i0 < NN) {
        offs[i0] = excl; cursor[i0] = excl;
        dinv[i0] = rsqrtf((float)v0);
    }
    if (i0 + 1 < NN) {
        offs[i0 + 1] = excl + v0; cursor[i0 + 1] = excl + v0;
        dinv[i0 + 1] = rsqrtf((float)v1);
    }
    if (blockIdx.x == SC_BLKS - 1 && t == 255) offs[NN] = excl + pair;
}

// ---------- CSR fill: store SRC directly (self-slots store d) ----------
__global__ void k_csr_fill(const int* __restrict__ src, const int* __restrict__ dst,
                           int* __restrict__ cursor, int* __restrict__ esrc)
{
    int gid = blockIdx.x * blockDim.x + threadIdx.x;
    if (gid >= EE + NN) return;
    int d, s;
    if (gid < EE) { d = dst[gid]; s = src[gid]; }
    else          { d = gid - EE; s = d; }
    int slot = atomicAdd(&cursor[d], 1);
    esrc[slot] = s;
}

// ---------- CSR gather with in-wave softmax; src stored in-slot ----------
__global__ __launch_bounds__(256) void k_gather(
    const int* __restrict__ esrc, const int* __restrict__ offs,
    const float* __restrict__ a_s, const float* __restrict__ a_d,
    const float* __restrict__ dinv,
    const ushort* __restrict__ xb,
    ushort* __restrict__ tgb, ushort* __restrict__ tcb,
    ushort* __restrict__ tsb)
{
    int d = blockIdx.x * 4 + (threadIdx.x >> 6);
    if (d >= NN) return;
    int lane = threadIdx.x & 63;
    int beg = offs[d], end = offs[d + 1];
    float ad = a_d[d], dd = dinv[d];

    int idx0 = beg + lane;
    bool v0 = idx0 < end;
    int s0 = d; float e0 = 0.f, wc0 = 0.f;
    if (v0) {
        s0 = esrc[idx0];
        float e = a_s[s0] + ad;
        e0 = (e > 0.f) ? e : 0.2f * e;
        wc0 = dinv[s0] * dd;
    }
    float m = v0 ? e0 : -3.0e38f;
    for (int base = beg + 64; base < end; base += 64) {
        int idx = base + lane;
        if (idx < end) {
            int s = esrc[idx];
            float e = a_s[s] + ad;
            e = (e > 0.f) ? e : 0.2f * e;
            m = fmaxf(m, e);
        }
    }
    #pragma unroll
    for (int off = 1; off < 64; off <<= 1) m = fmaxf(m, __shfl_xor(m, off));
    float ex0 = v0 ? expf(e0 - m) : 0.f;
    float den = ex0;
    for (int base = beg + 64; base < end; base += 64) {
        int idx = base + lane;
        if (idx < end) {
            int s = esrc[idx];
            float e = a_s[s] + ad;
            e = (e > 0.f) ? e : 0.2f * e;
            den += expf(e - m);
        }
    }
    #pragma unroll
    for (int off = 1; off < 64; off <<= 1) den += __shfl_xor(den, off);
    float rden = 1.f / den;

    float2 tg = {0.f, 0.f}, tc = {0.f, 0.f}, ts = {0.f, 0.f};
    int c = lane * 2;
    {
        float wg = ex0 * rden;      // 0 when invalid (ex0 = 0)
        float wc = wc0;
        int cnt = end - beg; if (cnt > 64) cnt = 64;
        for (int j = 0; j < cnt; ++j) {
            int   sj  = __shfl(s0, j);
            float wgj = __shfl(wg, j);
            float wcj = __shfl(wc, j);
            ushort2 xu = *(const ushort2*)(xb + (size_t)sj * 128 + c);
            float xvx = b2f(xu.x), xvy = b2f(xu.y);
            tg.x += wgj * xvx; tg.y += wgj * xvy;
            tc.x += wcj * xvx; tc.y += wcj * xvy;
            ts.x += xvx;       ts.y += xvy;
        }
    }
    for (int base = beg + 64; base < end; base += 64) {
        int idx = base + lane;
        int s = d; float wg = 0.f, wc = 0.f;
        if (idx < end) {
            s = esrc[idx];
            float e = a_s[s] + ad;
            e = (e > 0.f) ? e : 0.2f * e;
            wg = expf(e - m) * rden;
            wc = dinv[s] * dd;
        }
        int cnt = end - base; if (cnt > 64) cnt = 64;
        for (int j = 0; j < cnt; ++j) {
            int   sj  = __shfl(s, j);
            float wgj = __shfl(wg, j);
            float wcj = __shfl(wc, j);
            ushort2 xu = *(const ushort2*)(xb + (size_t)sj * 128 + c);
            float xvx = b2f(xu.x), xvy = b2f(xu.y);
            tg.x += wgj * xvx; tg.y += wgj * xvy;
            tc.x += wcj * xvx; tc.y += wcj * xvy;
            ts.x += xvx;       ts.y += xvy;
        }
    }
    ushort2 xdu = *(const ushort2*)(xb + (size_t)d * 128 + c);
    ts.x -= b2f(xdu.x); ts.y -= b2f(xdu.y);
    int cs = (end - beg) - 1;
    float rc = 1.f / (float)(cs > 1 ? cs : 1);
    ts.x *= rc; ts.y *= rc;

    size_t row = (size_t)d * 128 + c;
    { ushort2 u; u.x = f2b(tg.x); u.y = f2b(tg.y); *(ushort2*)(tgb + row) = u; }
    { ushort2 u; u.x = f2b(tc.x); u.y = f2b(tc.y); *(ushort2*)(tcb + row) = u; }
    { ushort2 u; u.x = f2b(ts.x); u.y = f2b(ts.y); *(ushort2*)(tsb + row) = u; }
}

// ---------- BN final: reduce per-block partials, fold gamma/beta ----------
__global__ void k_bn_final(const float* __restrict__ pS, const float* __restrict__ pQ,
                           const float* __restrict__ gamma, const float* __restrict__ beta,
                           float* __restrict__ scale, float* __restrict__ shift)
{
    int j = threadIdx.x;
    if (j >= C3) return;
    float s = 0.f, q = 0.f;
    for (int r = 0; r < NBLK; ++r) {
        s += pS[(size_t)r * C3 + j];
        q += pQ[(size_t)r * C3 + j];
    }
    const float rn = 1.f / (float)NN;
    float mu  = s * rn;
    float var = q * rn - mu * mu;
    float sc  = gamma[j] * rsqrtf(var + 1e-5f);
    scale[j] = sc;
    shift[j] = beta[j] - mu * sc;
}

// ---------- in-place BN+relu of hcat (8 elems/thread, 16B ld/st) ----------
__global__ __launch_bounds__(256) void k_bnrelu(
    ushort* __restrict__ hch,
    const float* __restrict__ scale, const float* __restrict__ shift)
{
    int p = blockIdx.x * blockDim.x + threadIdx.x;
    if (p >= NN * 48) return;
    int cidx = (p % 48) * 8;
    size_t o = (size_t)p * 8;
    uint4 w = *(uint4*)(hch + o);
    uint wr[4] = {w.x, w.y, w.z, w.w};
    uint out[4];
    #pragma unroll
    for (int i = 0; i < 4; ++i) {
        float4 sc = *(const float4*)(scale + cidx + i * 2 - (i & 1) * 2);   // unused; replaced below
        (void)sc;
        ushort u0 = (ushort)(wr[i] & 0xffffu), u1 = (ushort)(wr[i] >> 16);
        int cc = cidx + i * 2;
        float v0 = b2f(u0) * scale[cc]     + shift[cc];
        float v1 = b2f(u1) * scale[cc + 1] + shift[cc + 1];
        v0 = v0 > 0.f ? v0 : 0.f;
        v1 = v1 > 0.f ? v1 : 0.f;
        out[i] = (uint)f2b(v0) | ((uint)f2b(v1) << 16);
    }
    uint4 r; r.x = out[0]; r.y = out[1]; r.z = out[2]; r.w = out[3];
    *(uint4*)(hch + o) = r;
}

extern "C" void kernel_launch(void* const* d_in, const int* in_sizes, int n_in,
                              void* d_out, int out_size, void* d_ws, size_t ws_size,
                              hipStream_t stream) {
    const float* x        = (const float*)d_in[0];
    const int*   ei       = (const int*)d_in[1];
    const float* W_gat    = (const float*)d_in[2];
    const float* att_src  = (const float*)d_in[3];
    const float* att_dst  = (const float*)d_in[4];
    const float* b_gat    = (const float*)d_in[5];
    const float* W_gcn    = (const float*)d_in[6];
    const float* b_gcn    = (const float*)d_in[7];
    const float* W_sage_l = (const float*)d_in[8];
    const float* b_sage_l = (const float*)d_in[9];
    const float* W_sage_r = (const float*)d_in[10];
    const float* W1       = (const float*)d_in[11];
    const float* b1       = (const float*)d_in[12];
    const float* W2       = (const float*)d_in[13];
    const float* b2       = (const float*)d_in[14];
    const float* W3       = (const float*)d_in[15];
    const float* b3       = (const float*)d_in[16];
    const float* gamma    = (const float*)d_in[17];
    const float* beta     = (const float*)d_in[18];

    const int* e_src = ei;
    const int* e_dst = ei + EE;

    // ---- workspace layout (16B-aligned) ----
    char* base = (char*)d_ws;
    size_t o = 0;
    ushort* hch  = (ushort*)(base + o); o += (size_t)NN * C3 * 2;
    ushort* tgb  = (ushort*)(base + o); o += (size_t)NN * 128 * 2;    // a1 overlay
    ushort* tcb  = (ushort*)(base + o); o += (size_t)NN * 128 * 2;
    ushort* tsb  = (ushort*)(base + o); o += (size_t)NN * 128 * 2;    // a2 overlay
    ushort* xb   = (ushort*)(base + o); o += (size_t)NN * 128 * 2;
    int*    esrc = (int*)(base + o);    o += (size_t)(EE + NN) * 4;
    int*    offs = (int*)(base + o);    o += (size_t)(NN + 16) * 4;
    int*    cursor=(int*)(base + o);    o += (size_t)NN * 4;
    float*  as_  = (float*)(base + o);  o += (size_t)NN * 4;
    float*  ad_  = (float*)(base + o);  o += (size_t)NN * 4;
    float*  dinv = (float*)(base + o);  o += (size_t)NN * 4;
    int*    bsum = (int*)(base + o);    o += 256 * 4;
    int*    boffs= (int*)(base + o);    o += 256 * 4;
    // --- zero-init region: degA only ---
    int*    degA = (int*)(base + o);    o += (size_t)NN * 4;
    // --- end zero region ---
    float*  pS   = (float*)(base + o);  o += (size_t)NBLK * C3 * 4;   // written fully
    float*  pQ   = (float*)(base + o);  o += (size_t)NBLK * C3 * 4;
    float*  scale= (float*)(base + o);  o += C3 * 4;
    float*  shift= (float*)(base + o);  o += C3 * 4;
    float*  w_as = (float*)(base + o);  o += 128 * 4;
    float*  w_ad = (float*)(base + o);  o += 128 * 4;
    ushort* btg  = (ushort*)(base + o); o += 128 * 128 * 2;
    ushort* btc  = (ushort*)(base + o); o += 128 * 128 * 2;
    ushort* btsg = (ushort*)(base + o); o += 128 * 256 * 2;
    ushort* bt1  = (ushort*)(base + o); o += 256 * 384 * 2;
    ushort* bt2  = (ushort*)(base + o); o += 128 * 256 * 2;
    ushort* bt3  = (ushort*)(base + o); o += 48 * 128 * 2;
    // overlays (temporally disjoint)
    ushort* a1 = tgb;                        // NN*256 ushorts (tgb+tcb)
    ushort* a2 = tsb;                        // NN*128

    hipMemsetAsync(degA, 0, (size_t)NN * 4, stream);

    // ---- weight prep ----
    k_splitw_all<<<817, 256, 0, stream>>>(W_gat, W_gcn, W_sage_l, W_sage_r, W1, W2, W3,
        att_src, att_dst, w_as, w_ad, btg, btc, btsg, bt1, bt2, bt3);
    // split x + attention dots + degree histogram (merged)
    k_split_x_att<<<SPLIT_BLKS + HIST_BLKS, 256, 0, stream>>>(
        x, w_as, w_ad, e_dst, degA, xb, as_, ad_);

    // ---- CSR build ----
    k_scan_part<<<SC_BLKS, 256, 0, stream>>>(degA, bsum);
    k_scan_tops<<<1, 128, 0, stream>>>(bsum, boffs);
    k_scan_apply<<<SC_BLKS, 256, 0, stream>>>(degA, boffs, offs, cursor, dinv);
    k_csr_fill<<<(EE + NN + 255) / 256, 256, 0, stream>>>(e_src, e_dst, cursor, esrc);

    // ---- gather (bf16 x, direct-src CSR) ----
    k_gather<<<(NN + 3) / 4, 256, 0, stream>>>(
        esrc, offs, as_, ad_, dinv, xb, tgb, tcb, tsb);

    // ---- producers: one launch, privatized BN partials ----
    k_gemm_prod<<<dim3(NBLK, 1, 3), 256, 0, stream>>>(
        tgb, tcb, tsb, xb, btg, btc, btsg,
        b_gat, b_gcn, b_sage_l, pS, pQ, hch);

    // ---- BN fold (partials reduce) + standalone BN+relu pass ----
    k_bn_final<<<1, C3, 0, stream>>>(pS, pQ, gamma, beta, scale, shift);
    k_bnrelu<<<(NN * 48 + 255) / 256, 256, 0, stream>>>(hch, scale, shift);

    // ---- MLP ----
    k_gemm2<8, 3, 1><<<dim3(2, NBLK), 256, 0, stream>>>(
        hch, 384, bt1, NN, 0, b1, nullptr, 0, a1, 256, 256);
    k_gemm2<8, 2, 0><<<dim3(NBLK, 1), 256, 0, stream>>>(
        a1, 256, bt2, NN, 0, b2, nullptr, 0, a2, 128, 128);
    k_gemm2<3, 1, 0><<<dim3(NBLK, 1), 256, 0, stream>>>(
        a2, 128, bt3, NN, 2, b3, (float*)d_out, NOUT, nullptr, 0, NOUT);
}

// Round 19
// 417.286 us; speedup vs baseline: 1.0512x; 1.0103x over previous
//
#include <hip/hip_runtime.h>
#include <cstdint>
#include <cstddef>

#define NN   50000
#define FIN  128
#define HD   128
#define EE   800000
#define C3   384   // 3*H
#define NOUT 40

#define SC_ELEMS 512
#define SC_BLKS  ((NN + SC_ELEMS - 1) / SC_ELEMS)   // 98
#define NBLK ((NN + 127) / 128)                     // 391 row-blocks

#define SPLIT_BLKS ((NN + 3) / 4)                   // 12500
#define HIST_BLKS  ((EE + 255) / 256)               // 3125

#define LDSW 132   // padded epilogue LDS row stride (ushorts)

typedef __attribute__((ext_vector_type(8))) short s8v;   // 8 x bf16 (4 VGPR)
typedef __attribute__((ext_vector_type(4))) float f4v;   // MFMA acc

typedef const __attribute__((address_space(1))) unsigned int* guintp;
typedef __attribute__((address_space(3))) unsigned int* luintp;

static __device__ __forceinline__ void async_copy16(const void* g, void* l) {
    __builtin_amdgcn_global_load_lds((guintp)g, (luintp)l, 16, 0, 0);
}

// ---------- bf16 helpers ----------
static __device__ __forceinline__ float b2f(ushort u) {
    return __uint_as_float((unsigned)u << 16);
}
static __device__ __forceinline__ ushort f2b(float v) {
    unsigned u = __float_as_uint(v);
    unsigned r = u + 0x7fffu + ((u >> 16) & 1u);
    return (ushort)(r >> 16);
}

// ---------- merged: x -> bf16, attention dots, AND dst-degree histogram ----------
__global__ __launch_bounds__(256) void k_split_x_att(
    const float* __restrict__ x,
    const float* __restrict__ w_as, const float* __restrict__ w_ad,
    const int* __restrict__ e_dst, int* __restrict__ degA,
    ushort* __restrict__ xb,
    float* __restrict__ a_s, float* __restrict__ a_d)
{
    if (blockIdx.x >= SPLIT_BLKS) {
        int gid = (blockIdx.x - SPLIT_BLKS) * 256 + threadIdx.x;
        if (gid < EE) atomicAdd(&degA[e_dst[gid]], 1);
        return;
    }
    int node = blockIdx.x * 4 + (threadIdx.x >> 6);
    if (node >= NN) return;
    int lane = threadIdx.x & 63;
    size_t o = (size_t)node * 128 + lane * 2;
    float2 v  = *(const float2*)(x + o);
    { ushort2 u; u.x = f2b(v.x); u.y = f2b(v.y); *(ushort2*)(xb + o) = u; }
    float2 w1 = *(const float2*)(w_as + lane * 2);
    float2 w2 = *(const float2*)(w_ad + lane * 2);
    float s1 = v.x * w1.x + v.y * w1.y;
    float s2 = v.x * w2.x + v.y * w2.y;
    #pragma unroll
    for (int off = 32; off; off >>= 1) {
        s1 += __shfl_down(s1, off);
        s2 += __shfl_down(s2, off);
    }
    if (lane == 0) { a_s[node] = s1; a_d[node] = s2; }
}

// ---------- weight transposes (single bf16 plane) + att fold ----------
__global__ void k_splitw_all(
    const float* __restrict__ Wg, const float* __restrict__ Wc,
    const float* __restrict__ Wl, const float* __restrict__ Wr,
    const float* __restrict__ W1, const float* __restrict__ W2,
    const float* __restrict__ W3,
    const float* __restrict__ asv, const float* __restrict__ adv,
    float* __restrict__ w_as, float* __restrict__ w_ad,
    ushort* __restrict__ btg, ushort* __restrict__ btc,
    ushort* __restrict__ btsg,
    ushort* __restrict__ bt1, ushort* __restrict__ bt2,
    ushort* __restrict__ bt3)
{
    int ry = blockIdx.x;
    int t = threadIdx.x;
    if (ry == 816) {
        if (t < 128) {
            float s1 = 0.f, s2 = 0.f;
            for (int j = 0; j < 128; ++j) {
                float w = Wg[t * 128 + j];
                s1 += w * asv[j];
                s2 += w * adv[j];
            }
            w_as[t] = s1; w_ad[t] = s2;
        }
        return;
    }
    const float* W = nullptr; ushort* dh; int K, Nw, n;
    bool sage = false;
    if (ry < 128)      { n = ry;       K = 128; Nw = 128; W = Wg; dh = btg; }
    else if (ry < 256) { n = ry - 128; K = 128; Nw = 128; W = Wc; dh = btc; }
    else if (ry < 384) { n = ry - 256; K = 256; Nw = 128; sage = true; dh = btsg; }
    else if (ry < 640) { n = ry - 384; K = 384; Nw = 256; W = W1; dh = bt1; }
    else if (ry < 768) { n = ry - 640; K = 256; Nw = 128; W = W2; dh = bt2; }
    else               { n = ry - 768; K = 128; Nw = 40;  W = W3; dh = bt3; }
    for (int k = t; k < K; k += 256) {
        float v;
        if (sage) v = (k < 128) ? Wl[(size_t)k * 128 + n] : Wr[(size_t)(k - 128) * 128 + n];
        else      v = (n < Nw) ? W[(size_t)k * Nw + n] : 0.f;
        dh[(size_t)n * K + k] = f2b(v);
    }
}

// ---------- MFMA GEMM: bf16 A and B, both DMA-staged via LDS ----------
// mode 0: relu(acc+bias) -> bf16 store; mode 2: acc+bias -> fp32, cols<colmax
template<int NT, int NCH, int AX>
__global__ __launch_bounds__(256, 5) void k_gemm2(
    const ushort* __restrict__ A, int K,
    const ushort* __restrict__ Bt,
    int M, int mode,
    const float* __restrict__ bias,
    float* __restrict__ Cf, int ldc,
    ushort* __restrict__ Ch, int ldch,
    int colmax)
{
    constexpr int COLS = NT * 16;
    constexpr int HOPU = 8 * COLS;       // B 16B-units per 64-k half (1 plane)
    constexpr int KTOT = NCH * 128;

    __shared__ __align__(16) ushort S[16384];   // 32 KB union
    ushort* Bs = S;
    ushort* As = S + 8192;

    const int lane = threadIdx.x & 63;
    const int wave = threadIdx.x >> 6;
    const int quad = lane >> 4;
    const int ln15 = lane & 15;
    const int brow = AX ? blockIdx.y : blockIdx.x;
    const int bcol = AX ? blockIdx.x : blockIdx.y;
    const int row0 = brow * 128 + wave * 32;
    const int col0 = bcol * COLS;
    const int Rbase = brow * 128;

    auto stageB = [&](int c, int h) {
        for (int u0 = wave * 64; u0 < HOPU; u0 += 256) {
            int u  = u0 + lane;
            int kq  = u / COLS;
            int col = u - kq * COLS;
            int kk  = c * 128 + h * 64 + kq * 8;
            const ushort* gp = Bt + (size_t)(col0 + col) * KTOT + kk;
            async_copy16(gp, (char*)Bs + (size_t)u0 * 16);
        }
    };
    auto stageA = [&](int c, int h) {
        #pragma unroll
        for (int i = 0; i < 4; ++i) {
            int u0 = (wave * 4 + i) * 64;
            int u  = u0 + lane;
            int row = u >> 3;
            int s   = u & 7;
            int sg  = s ^ (row & 7);
            int rr = Rbase + row; if (rr > M - 1) rr = M - 1;
            int kk = c * 128 + h * 64 + sg * 8;
            const ushort* gp = A + (size_t)rr * K + kk;
            async_copy16(gp, (char*)As + (size_t)u0 * 16);
        }
    };
    auto afrag = [&](int jj, int mt) -> s8v {
        int r = wave * 32 + mt * 16 + ln15;
        int sg = jj * 4 + quad;
        int unit = r * 8 + (sg ^ (r & 7));
        return *(const s8v*)(As + (size_t)unit * 8);
    };

    f4v acc[2][NT] = {};

    auto compute = [&](int jj) {
        s8v a0 = afrag(jj, 0);
        s8v a1 = afrag(jj, 1);
        #pragma unroll
        for (int t = 0; t < NT; ++t) {
            int ub = (jj * 4 + quad) * COLS + t * 16 + ln15;
            s8v b = *(const s8v*)(Bs + (size_t)ub * 8);
            acc[0][t] = __builtin_amdgcn_mfma_f32_16x16x32_bf16(a0, b, acc[0][t], 0, 0, 0);
            acc[1][t] = __builtin_amdgcn_mfma_f32_16x16x32_bf16(a1, b, acc[1][t], 0, 0, 0);
        }
    };

    stageB(0, 0); stageA(0, 0);
    __syncthreads();

    #pragma unroll
    for (int ph = 0; ph < NCH; ++ph) {
        #pragma unroll
        for (int h = 0; h < 2; ++h) {
            compute(0); compute(1);
            if (!(ph == NCH - 1 && h == 1)) {
                __syncthreads();
                int nc = ph, nh = h + 1;
                if (nh == 2) { nh = 0; ++nc; }
                stageB(nc, nh); stageA(nc, nh);
                __syncthreads();
            }
        }
    }

    if (NT == 8 && mode == 0) {
        __syncthreads();                          // staging LDS free now
        ushort* Lp = S + wave * 2176;             // wave-private quarter
        #pragma unroll
        for (int mt = 0; mt < 2; ++mt) {
            #pragma unroll
            for (int t = 0; t < NT; ++t) {
                int cc = col0 + t * 16 + ln15;
                #pragma unroll
                for (int r = 0; r < 4; ++r) {
                    float v = acc[mt][t][r] + bias[cc];
                    v = v > 0.f ? v : 0.f;
                    Lp[(quad * 4 + r) * LDSW + t * 16 + ln15] = f2b(v);
                }
            }
            int cb = (lane & 31) * 4;
            #pragma unroll
            for (int it = 0; it < 8; ++it) {
                int row2 = it * 2 + (lane >> 5);
                int rr = row0 + mt * 16 + row2;
                uint2 v = *(uint2*)(Lp + row2 * LDSW + cb);
                if (rr < M)
                    *(uint2*)(Ch + (size_t)rr * ldch + col0 + cb) = v;
            }
        }
    } else {
        #pragma unroll
        for (int t = 0; t < NT; ++t) {
            int cc = col0 + t * 16 + ln15;
            #pragma unroll
            for (int mt = 0; mt < 2; ++mt) {
                #pragma unroll
                for (int r = 0; r < 4; ++r) {
                    int rr = row0 + mt * 16 + quad * 4 + r;
                    if (rr < M && cc < colmax)
                        Cf[(size_t)rr * ldc + cc] = acc[mt][t][r] + bias[cc];
                }
            }
        }
    }
}

// ---------- merged producer GEMMs: z=0 GAT, z=1 GCN, z=2 SAGE ----------
// launch_bounds(256,3): keeps z0+z1 L2-resident hand-off (R14 lesson).
__global__ __launch_bounds__(256, 3) void k_gemm_prod(
    const ushort* __restrict__ tgb, const ushort* __restrict__ tcb,
    const ushort* __restrict__ tsb, const ushort* __restrict__ xb,
    const ushort* __restrict__ btg, const ushort* __restrict__ btc,
    const ushort* __restrict__ btsg,
    const float* __restrict__ bg, const float* __restrict__ bc,
    const float* __restrict__ bsl,
    float* __restrict__ pS, float* __restrict__ pQ,   // [NBLK][C3] partials
    ushort* __restrict__ hch)
{
    constexpr int COLS = 128;
    constexpr int HOPU = 8 * COLS;               // 1024 units per half
    __shared__ __align__(16) ushort S[16384];    // 32 KB union
    ushort* Bs = S;
    ushort* As = S + 8192;
    float* red = (float*)(S + 14336);            // 256 floats (dead As region)

    const int z = blockIdx.z;
    const ushort* A1 = (z == 0) ? tgb : (z == 1) ? tcb : tsb;
    const ushort* Bt = (z == 0) ? btg : (z == 1) ? btc : btsg;
    const float*  bias = (z == 0) ? bg : (z == 1) ? bc : bsl;
    const int nch = (z == 2) ? 2 : 1;
    const int ktot = nch * 128;

    const int lane = threadIdx.x & 63;
    const int wave = threadIdx.x >> 6;
    const int quad = lane >> 4;
    const int ln15 = lane & 15;
    const int row0 = blockIdx.x * 128 + wave * 32;
    const int Rbase = blockIdx.x * 128;

    auto stageB = [&](int c, int h) {
        for (int u0 = wave * 64; u0 < HOPU; u0 += 256) {
            int u  = u0 + lane;
            int kq  = u / COLS;
            int col = u - kq * COLS;
            int kk  = c * 128 + h * 64 + kq * 8;
            const ushort* gp = Bt + (size_t)col * ktot + kk;
            async_copy16(gp, (char*)Bs + (size_t)u0 * 16);
        }
    };
    auto stageA = [&](int c, int h) {
        #pragma unroll
        for (int i = 0; i < 4; ++i) {
            int u0 = (wave * 4 + i) * 64;
            int u  = u0 + lane;
            int row = u >> 3;
            int s   = u & 7;
            int sg  = s ^ (row & 7);
            int rr = Rbase + row; if (rr > NN - 1) rr = NN - 1;
            int kk = c * 128 + h * 64 + sg * 8;
            const ushort* gp = (kk < 128) ? (A1 + (size_t)rr * 128 + kk)
                                          : (xb + (size_t)rr * 128 + (kk - 128));
            async_copy16(gp, (char*)As + (size_t)u0 * 16);
        }
    };
    auto afrag = [&](int jj, int mt) -> s8v {
        int r = wave * 32 + mt * 16 + ln15;
        int sg = jj * 4 + quad;
        int unit = r * 8 + (sg ^ (r & 7));
        return *(const s8v*)(As + (size_t)unit * 8);
    };

    f4v acc[2][8] = {};

    auto compute = [&](int jj) {
        s8v a0 = afrag(jj, 0);
        s8v a1 = afrag(jj, 1);
        #pragma unroll
        for (int t = 0; t < 8; ++t) {
            int ub = (jj * 4 + quad) * COLS + t * 16 + ln15;
            s8v b = *(const s8v*)(Bs + (size_t)ub * 8);
            acc[0][t] = __builtin_amdgcn_mfma_f32_16x16x32_bf16(a0, b, acc[0][t], 0, 0, 0);
            acc[1][t] = __builtin_amdgcn_mfma_f32_16x16x32_bf16(a1, b, acc[1][t], 0, 0, 0);
        }
    };

    stageB(0, 0); stageA(0, 0);
    __syncthreads();

    for (int ph = 0; ph < nch; ++ph) {
        for (int h = 0; h < 2; ++h) {
            compute(0); compute(1);
            if (!(ph == nch - 1 && h == 1)) {
                __syncthreads();
                int nc = ph, nh = h + 1;
                if (nh == 2) { nh = 0; ++nc; }
                stageB(nc, nh); stageA(nc, nh);
                __syncthreads();
            }
        }
    }

    // LDS-transpose epilogue + per-lane BN partials
    __syncthreads();
    if (threadIdx.x < 256) red[threadIdx.x] = 0.f;   // As dead; red disjoint from Lp
    ushort* Lp = S + wave * 2176;
    float sp[8] = {}, qp[8] = {};
    #pragma unroll
    for (int mt = 0; mt < 2; ++mt) {
        #pragma unroll
        for (int t = 0; t < 8; ++t) {
            #pragma unroll
            for (int r = 0; r < 4; ++r) {
                int rr = row0 + mt * 16 + quad * 4 + r;
                float v = acc[mt][t][r] + bias[t * 16 + ln15];
                Lp[(quad * 4 + r) * LDSW + t * 16 + ln15] = f2b(v);
                if (rr < NN) { sp[t] += v; qp[t] += v * v; }
            }
        }
        int cb = (lane & 31) * 4;
        #pragma unroll
        for (int it = 0; it < 8; ++it) {
            int row2 = it * 2 + (lane >> 5);
            int rr = row0 + mt * 16 + row2;
            uint2 v = *(uint2*)(Lp + row2 * LDSW + cb);
            if (rr < NN)
                *(uint2*)(hch + (size_t)rr * C3 + z * 128 + cb) = v;
        }
    }
    // cross-wave LDS reduce (no contended global atomics)
    __syncthreads();
    #pragma unroll
    for (int t = 0; t < 8; ++t) {
        float s = sp[t], q = qp[t];
        s += __shfl_xor(s, 16); s += __shfl_xor(s, 32);
        q += __shfl_xor(q, 16); q += __shfl_xor(q, 32);
        if (quad == 0) {
            atomicAdd(&red[t * 16 + ln15], s);          // LDS atomic
            atomicAdd(&red[128 + t * 16 + ln15], q);
        }
    }
    __syncthreads();
    if (threadIdx.x < 128) {
        size_t o = (size_t)blockIdx.x * C3 + z * 128 + threadIdx.x;
        pS[o] = red[threadIdx.x];
        pQ[o] = red[128 + threadIdx.x];
    }
}

// ---------- hierarchical exclusive scan over (degA[i]+1) ----------
__global__ __launch_bounds__(256) void k_scan_part(
    const int* __restrict__ degA, int* __restrict__ bsum)
{
    int t = threadIdx.x;
    int b0 = blockIdx.x * SC_ELEMS;
    int i0 = b0 + t * 2;
    int v0 = (i0 < NN)     ? degA[i0] + 1     : 0;
    int v1 = (i0 + 1 < NN) ? degA[i0 + 1] + 1 : 0;
    int s = v0 + v1;
    #pragma unroll
    for (int off = 32; off; off >>= 1) s += __shfl_down(s, off);
    __shared__ int ws[4];
    if ((t & 63) == 0) ws[t >> 6] = s;
    __syncthreads();
    if (t == 0) bsum[blockIdx.x] = ws[0] + ws[1] + ws[2] + ws[3];
}

__global__ __launch_bounds__(128) void k_scan_tops(
    const int* __restrict__ bsum, int* __restrict__ boffs)
{
    __shared__ int sh[128];
    int t = threadIdx.x;
    int v = (t < SC_BLKS) ? bsum[t] : 0;
    sh[t] = v;
    __syncthreads();
    for (int off = 1; off < 128; off <<= 1) {
        int u = (t >= off) ? sh[t - off] : 0;
        __syncthreads();
        sh[t] += u;
        __syncthreads();
    }
    if (t < SC_BLKS) boffs[t] = sh[t] - v;   // exclusive
    if (t == SC_BLKS - 1) boffs[SC_BLKS] = sh[t];
}

__global__ __launch_bounds__(256) void k_scan_apply(
    const int* __restrict__ degA, const int* __restrict__ boffs,
    int* __restrict__ offs, int* __restrict__ cursor,
    float* __restrict__ dinv)
{
    __shared__ int sh[256];
    int t = threadIdx.x;
    int b0 = blockIdx.x * SC_ELEMS;
    int i0 = b0 + t * 2;
    int v0 = (i0 < NN)     ? degA[i0] + 1     : 0;
    int v1 = (i0 + 1 < NN) ? degA[i0 + 1] + 1 : 0;
    int pair = v0 + v1;
    sh[t] = pair;
    __syncthreads();
    for (int off = 1; off < 256; off <<= 1) {
        int u = (t >= off) ? sh[t - off] : 0;
        __syncthreads();
        sh[t] += u;
        __syncthreads();
    }
    int excl = sh[t] - pair + boffs[blockIdx.x];
    if (i0 < NN) {
        offs[i0] = excl; cursor[i0] = excl;
        dinv[i0] = rsqrtf((float)v0);
    }
    if (i0 + 1 < NN) {
        offs[i0 + 1] = excl + v0; cursor[i0 + 1] = excl + v0;
        dinv[i0 + 1] = rsqrtf((float)v1);
    }
    if (blockIdx.x == SC_BLKS - 1 && t == 255) offs[NN] = excl + pair;
}

// ---------- CSR fill: store SRC directly (self-slots store d) ----------
__global__ void k_csr_fill(const int* __restrict__ src, const int* __restrict__ dst,
                           int* __restrict__ cursor, int* __restrict__ esrc)
{
    int gid = blockIdx.x * blockDim.x + threadIdx.x;
    if (gid >= EE + NN) return;
    int d, s;
    if (gid < EE) { d = dst[gid]; s = src[gid]; }
    else          { d = gid - EE; s = d; }
    int slot = atomicAdd(&cursor[d], 1);
    esrc[slot] = s;
}

// ---------- CSR gather with in-wave softmax; 2-shuffle packed weights ----------
__global__ __launch_bounds__(256) void k_gather(
    const int* __restrict__ esrc, const int* __restrict__ offs,
    const float* __restrict__ a_s, const float* __restrict__ a_d,
    const float* __restrict__ dinv,
    const ushort* __restrict__ xb,
    ushort* __restrict__ tgb, ushort* __restrict__ tcb,
    ushort* __restrict__ tsb)
{
    int d = blockIdx.x * 4 + (threadIdx.x >> 6);
    if (d >= NN) return;
    int lane = threadIdx.x & 63;
    int beg = offs[d], end = offs[d + 1];
    float ad = a_d[d], dd = dinv[d];

    int idx0 = beg + lane;
    bool v0 = idx0 < end;
    int s0 = d; float e0 = 0.f, wc0 = 0.f;
    if (v0) {
        s0 = esrc[idx0];
        float e = a_s[s0] + ad;
        e0 = (e > 0.f) ? e : 0.2f * e;
        wc0 = dinv[s0] * dd;
    }
    float m = v0 ? e0 : -3.0e38f;
    for (int base = beg + 64; base < end; base += 64) {
        int idx = base + lane;
        if (idx < end) {
            int s = esrc[idx];
            float e = a_s[s] + ad;
            e = (e > 0.f) ? e : 0.2f * e;
            m = fmaxf(m, e);
        }
    }
    #pragma unroll
    for (int off = 1; off < 64; off <<= 1) m = fmaxf(m, __shfl_xor(m, off));
    float ex0 = v0 ? expf(e0 - m) : 0.f;
    float den = ex0;
    for (int base = beg + 64; base < end; base += 64) {
        int idx = base + lane;
        if (idx < end) {
            int s = esrc[idx];
            float e = a_s[s] + ad;
            e = (e > 0.f) ? e : 0.2f * e;
            den += expf(e - m);
        }
    }
    #pragma unroll
    for (int off = 1; off < 64; off <<= 1) den += __shfl_xor(den, off);
    float rden = 1.f / den;

    float2 tg = {0.f, 0.f}, tc = {0.f, 0.f}, ts = {0.f, 0.f};
    int c = lane * 2;
    {
        // pack (wg, wc) as 2 x bf16 -> ONE extra shuffle per edge instead of two
        float wg = ex0 * rden;      // 0 when invalid
        uint pw0 = (uint)f2b(wg) | ((uint)f2b(wc0) << 16);
        int cnt = end - beg; if (cnt > 64) cnt = 64;
        for (int j = 0; j < cnt; ++j) {
            int  sj  = __shfl(s0, j);
            uint pwj = __shfl(pw0, j);
            float wgj = b2f((ushort)(pwj & 0xffffu));
            float wcj = b2f((ushort)(pwj >> 16));
            ushort2 xu = *(const ushort2*)(xb + (size_t)sj * 128 + c);
            float xvx = b2f(xu.x), xvy = b2f(xu.y);
            tg.x += wgj * xvx; tg.y += wgj * xvy;
            tc.x += wcj * xvx; tc.y += wcj * xvy;
            ts.x += xvx;       ts.y += xvy;
        }
    }
    for (int base = beg + 64; base < end; base += 64) {
        int idx = base + lane;
        int s = d; uint pw = 0;
        if (idx < end) {
            s = esrc[idx];
            float e = a_s[s] + ad;
            e = (e > 0.f) ? e : 0.2f * e;
            float wg = expf(e - m) * rden;
            float wc = dinv[s] * dd;
            pw = (uint)f2b(wg) | ((uint)f2b(wc) << 16);
        }
        int cnt = end - base; if (cnt > 64) cnt = 64;
        for (int j = 0; j < cnt; ++j) {
            int  sj  = __shfl(s, j);
            uint pwj = __shfl(pw, j);
            float wgj = b2f((ushort)(pwj & 0xffffu));
            float wcj = b2f((ushort)(pwj >> 16));
            ushort2 xu = *(const ushort2*)(xb + (size_t)sj * 128 + c);
            float xvx = b2f(xu.x), xvy = b2f(xu.y);
            tg.x += wgj * xvx; tg.y += wgj * xvy;
            tc.x += wcj * xvx; tc.y += wcj * xvy;
            ts.x += xvx;       ts.y += xvy;
        }
    }
    ushort2 xdu = *(const ushort2*)(xb + (size_t)d * 128 + c);
    ts.x -= b2f(xdu.x); ts.y -= b2f(xdu.y);
    int cs = (end - beg) - 1;
    float rc = 1.f / (float)(cs > 1 ? cs : 1);
    ts.x *= rc; ts.y *= rc;

    size_t row = (size_t)d * 128 + c;
    { ushort2 u; u.x = f2b(tg.x); u.y = f2b(tg.y); *(ushort2*)(tgb + row) = u; }
    { ushort2 u; u.x = f2b(tc.x); u.y = f2b(tc.y); *(ushort2*)(tcb + row) = u; }
    { ushort2 u; u.x = f2b(ts.x); u.y = f2b(ts.y); *(ushort2*)(tsb + row) = u; }
}

// ---------- BN final: reduce per-block partials, fold gamma/beta ----------
__global__ void k_bn_final(const float* __restrict__ pS, const float* __restrict__ pQ,
                           const float* __restrict__ gamma, const float* __restrict__ beta,
                           float* __restrict__ scale, float* __restrict__ shift)
{
    int j = threadIdx.x;
    if (j >= C3) return;
    float s = 0.f, q = 0.f;
    for (int r = 0; r < NBLK; ++r) {
        s += pS[(size_t)r * C3 + j];
        q += pQ[(size_t)r * C3 + j];
    }
    const float rn = 1.f / (float)NN;
    float mu  = s * rn;
    float var = q * rn - mu * mu;
    float sc  = gamma[j] * rsqrtf(var + 1e-5f);
    scale[j] = sc;
    shift[j] = beta[j] - mu * sc;
}

// ---------- in-place BN+relu of hcat (8 elems/thread, 16B ld/st) ----------
__global__ __launch_bounds__(256) void k_bnrelu(
    ushort* __restrict__ hch,
    const float* __restrict__ scale, const float* __restrict__ shift)
{
    int p = blockIdx.x * blockDim.x + threadIdx.x;
    if (p >= NN * 48) return;
    int cidx = (p % 48) * 8;
    size_t o = (size_t)p * 8;
    uint4 w = *(uint4*)(hch + o);
    uint wr[4] = {w.x, w.y, w.z, w.w};
    uint out[4];
    #pragma unroll
    for (int i = 0; i < 4; ++i) {
        ushort u0 = (ushort)(wr[i] & 0xffffu), u1 = (ushort)(wr[i] >> 16);
        int cc = cidx + i * 2;
        float v0 = b2f(u0) * scale[cc]     + shift[cc];
        float v1 = b2f(u1) * scale[cc + 1] + shift[cc + 1];
        v0 = v0 > 0.f ? v0 : 0.f;
        v1 = v1 > 0.f ? v1 : 0.f;
        out[i] = (uint)f2b(v0) | ((uint)f2b(v1) << 16);
    }
    uint4 r; r.x = out[0]; r.y = out[1]; r.z = out[2]; r.w = out[3];
    *(uint4*)(hch + o) = r;
}

extern "C" void kernel_launch(void* const* d_in, const int* in_sizes, int n_in,
                              void* d_out, int out_size, void* d_ws, size_t ws_size,
                              hipStream_t stream) {
    const float* x        = (const float*)d_in[0];
    const int*   ei       = (const int*)d_in[1];
    const float* W_gat    = (const float*)d_in[2];
    const float* att_src  = (const float*)d_in[3];
    const float* att_dst  = (const float*)d_in[4];
    const float* b_gat    = (const float*)d_in[5];
    const float* W_gcn    = (const float*)d_in[6];
    const float* b_gcn    = (const float*)d_in[7];
    const float* W_sage_l = (const float*)d_in[8];
    const float* b_sage_l = (const float*)d_in[9];
    const float* W_sage_r = (const float*)d_in[10];
    const float* W1       = (const float*)d_in[11];
    const float* b1       = (const float*)d_in[12];
    const float* W2       = (const float*)d_in[13];
    const float* b2       = (const float*)d_in[14];
    const float* W3       = (const float*)d_in[15];
    const float* b3       = (const float*)d_in[16];
    const float* gamma    = (const float*)d_in[17];
    const float* beta     = (const float*)d_in[18];

    const int* e_src = ei;
    const int* e_dst = ei + EE;

    // ---- workspace layout (16B-aligned) ----
    char* base = (char*)d_ws;
    size_t o = 0;
    ushort* hch  = (ushort*)(base + o); o += (size_t)NN * C3 * 2;
    ushort* tgb  = (ushort*)(base + o); o += (size_t)NN * 128 * 2;    // a1 overlay
    ushort* tcb  = (ushort*)(base + o); o += (size_t)NN * 128 * 2;
    ushort* tsb  = (ushort*)(base + o); o += (size_t)NN * 128 * 2;    // a2 overlay
    ushort* xb   = (ushort*)(base + o); o += (size_t)NN * 128 * 2;
    int*    esrc = (int*)(base + o);    o += (size_t)(EE + NN) * 4;
    int*    offs = (int*)(base + o);    o += (size_t)(NN + 16) * 4;
    int*    cursor=(int*)(base + o);    o += (size_t)NN * 4;
    float*  as_  = (float*)(base + o);  o += (size_t)NN * 4;
    float*  ad_  = (float*)(base + o);  o += (size_t)NN * 4;
    float*  dinv = (float*)(base + o);  o += (size_t)NN * 4;
    int*    bsum = (int*)(base + o);    o += 256 * 4;
    int*    boffs= (int*)(base + o);    o += 256 * 4;
    // --- zero-init region: degA only ---
    int*    degA = (int*)(base + o);    o += (size_t)NN * 4;
    // --- end zero region ---
    float*  pS   = (float*)(base + o);  o += (size_t)NBLK * C3 * 4;   // written fully
    float*  pQ   = (float*)(base + o);  o += (size_t)NBLK * C3 * 4;
    float*  scale= (float*)(base + o);  o += C3 * 4;
    float*  shift= (float*)(base + o);  o += C3 * 4;
    float*  w_as = (float*)(base + o);  o += 128 * 4;
    float*  w_ad = (float*)(base + o);  o += 128 * 4;
    ushort* btg  = (ushort*)(base + o); o += 128 * 128 * 2;
    ushort* btc  = (ushort*)(base + o); o += 128 * 128 * 2;
    ushort* btsg = (ushort*)(base + o); o += 128 * 256 * 2;
    ushort* bt1  = (ushort*)(base + o); o += 256 * 384 * 2;
    ushort* bt2  = (ushort*)(base + o); o += 128 * 256 * 2;
    ushort* bt3  = (ushort*)(base + o); o += 48 * 128 * 2;
    // overlays (temporally disjoint)
    ushort* a1 = tgb;                        // NN*256 ushorts (tgb+tcb)
    ushort* a2 = tsb;                        // NN*128

    hipMemsetAsync(degA, 0, (size_t)NN * 4, stream);

    // ---- weight prep ----
    k_splitw_all<<<817, 256, 0, stream>>>(W_gat, W_gcn, W_sage_l, W_sage_r, W1, W2, W3,
        att_src, att_dst, w_as, w_ad, btg, btc, btsg, bt1, bt2, bt3);
    // split x + attention dots + degree histogram (merged)
    k_split_x_att<<<SPLIT_BLKS + HIST_BLKS, 256, 0, stream>>>(
        x, w_as, w_ad, e_dst, degA, xb, as_, ad_);

    // ---- CSR build ----
    k_scan_part<<<SC_BLKS, 256, 0, stream>>>(degA, bsum);
    k_scan_tops<<<1, 128, 0, stream>>>(bsum, boffs);
    k_scan_apply<<<SC_BLKS, 256, 0, stream>>>(degA, boffs, offs, cursor, dinv);
    k_csr_fill<<<(EE + NN + 255) / 256, 256, 0, stream>>>(e_src, e_dst, cursor, esrc);

    // ---- gather (bf16 x, direct-src CSR, packed-weight shuffles) ----
    k_gather<<<(NN + 3) / 4, 256, 0, stream>>>(
        esrc, offs, as_, ad_, dinv, xb, tgb, tcb, tsb);

    // ---- producers: one launch, privatized BN partials ----
    k_gemm_prod<<<dim3(NBLK, 1, 3), 256, 0, stream>>>(
        tgb, tcb, tsb, xb, btg, btc, btsg,
        b_gat, b_gcn, b_sage_l, pS, pQ, hch);

    // ---- BN fold (partials reduce) + standalone BN+relu pass ----
    k_bn_final<<<1, C3, 0, stream>>>(pS, pQ, gamma, beta, scale, shift);
    k_bnrelu<<<(NN * 48 + 255) / 256, 256, 0, stream>>>(hch, scale, shift);

    // ---- MLP ----
    k_gemm2<8, 3, 1><<<dim3(2, NBLK), 256, 0, stream>>>(
        hch, 384, bt1, NN, 0, b1, nullptr, 0, a1, 256, 256);
    k_gemm2<8, 2, 0><<<dim3(NBLK, 1), 256, 0, stream>>>(
        a1, 256, bt2, NN, 0, b2, nullptr, 0, a2, 128, 128);
    k_gemm2<3, 1, 0><<<dim3(NBLK, 1), 256, 0, stream>>>(
        a2, 128, bt3, NN, 2, b3, (float*)d_out, NOUT, nullptr, 0, NOUT);
}

// Round 20
// 397.344 us; speedup vs baseline: 1.1040x; 1.0502x over previous
//
#include <hip/hip_runtime.h>
#include <cstdint>
#include <cstddef>

#define NN   50000
#define FIN  128
#define HD   128
#define EE   800000
#define C3   384   // 3*H
#define NOUT 40

#define SC_ELEMS 512
#define SC_BLKS  ((NN + SC_ELEMS - 1) / SC_ELEMS)   // 98
#define NBLK ((NN + 127) / 128)                     // 391 row-blocks

#define SPLIT_BLKS ((NN + 3) / 4)                   // 12500
#define HIST_BLKS  ((EE + 255) / 256)               // 3125

#define LDSW 132   // padded epilogue LDS row stride (ushorts)

typedef __attribute__((ext_vector_type(8))) short s8v;   // 8 x bf16 (4 VGPR)
typedef __attribute__((ext_vector_type(4))) float f4v;   // MFMA acc

typedef const __attribute__((address_space(1))) unsigned int* guintp;
typedef __attribute__((address_space(3))) unsigned int* luintp;

static __device__ __forceinline__ void async_copy16(const void* g, void* l) {
    __builtin_amdgcn_global_load_lds((guintp)g, (luintp)l, 16, 0, 0);
}

// ---------- bf16 helpers ----------
static __device__ __forceinline__ float b2f(ushort u) {
    return __uint_as_float((unsigned)u << 16);
}
static __device__ __forceinline__ ushort f2b(float v) {
    unsigned u = __float_as_uint(v);
    unsigned r = u + 0x7fffu + ((u >> 16) & 1u);
    return (ushort)(r >> 16);
}

// ---------- merged: x -> bf16, attention dots, AND dst-degree histogram ----------
__global__ __launch_bounds__(256) void k_split_x_att(
    const float* __restrict__ x,
    const float* __restrict__ w_as, const float* __restrict__ w_ad,
    const int* __restrict__ e_dst, int* __restrict__ degA,
    ushort* __restrict__ xb,
    float* __restrict__ a_s, float* __restrict__ a_d)
{
    if (blockIdx.x >= SPLIT_BLKS) {
        int gid = (blockIdx.x - SPLIT_BLKS) * 256 + threadIdx.x;
        if (gid < EE) atomicAdd(&degA[e_dst[gid]], 1);
        return;
    }
    int node = blockIdx.x * 4 + (threadIdx.x >> 6);
    if (node >= NN) return;
    int lane = threadIdx.x & 63;
    size_t o = (size_t)node * 128 + lane * 2;
    float2 v  = *(const float2*)(x + o);
    { ushort2 u; u.x = f2b(v.x); u.y = f2b(v.y); *(ushort2*)(xb + o) = u; }
    float2 w1 = *(const float2*)(w_as + lane * 2);
    float2 w2 = *(const float2*)(w_ad + lane * 2);
    float s1 = v.x * w1.x + v.y * w1.y;
    float s2 = v.x * w2.x + v.y * w2.y;
    #pragma unroll
    for (int off = 32; off; off >>= 1) {
        s1 += __shfl_down(s1, off);
        s2 += __shfl_down(s2, off);
    }
    if (lane == 0) { a_s[node] = s1; a_d[node] = s2; }
}

// ---------- weight transposes (single bf16 plane) + att fold ----------
__global__ void k_splitw_all(
    const float* __restrict__ Wg, const float* __restrict__ Wc,
    const float* __restrict__ Wl, const float* __restrict__ Wr,
    const float* __restrict__ W1, const float* __restrict__ W2,
    const float* __restrict__ W3,
    const float* __restrict__ asv, const float* __restrict__ adv,
    float* __restrict__ w_as, float* __restrict__ w_ad,
    ushort* __restrict__ btg, ushort* __restrict__ btc,
    ushort* __restrict__ btsg,
    ushort* __restrict__ bt1, ushort* __restrict__ bt2,
    ushort* __restrict__ bt3)
{
    int ry = blockIdx.x;
    int t = threadIdx.x;
    if (ry == 816) {
        if (t < 128) {
            float s1 = 0.f, s2 = 0.f;
            for (int j = 0; j < 128; ++j) {
                float w = Wg[t * 128 + j];
                s1 += w * asv[j];
                s2 += w * adv[j];
            }
            w_as[t] = s1; w_ad[t] = s2;
        }
        return;
    }
    const float* W = nullptr; ushort* dh; int K, Nw, n;
    bool sage = false;
    if (ry < 128)      { n = ry;       K = 128; Nw = 128; W = Wg; dh = btg; }
    else if (ry < 256) { n = ry - 128; K = 128; Nw = 128; W = Wc; dh = btc; }
    else if (ry < 384) { n = ry - 256; K = 256; Nw = 128; sage = true; dh = btsg; }
    else if (ry < 640) { n = ry - 384; K = 384; Nw = 256; W = W1; dh = bt1; }
    else if (ry < 768) { n = ry - 640; K = 256; Nw = 128; W = W2; dh = bt2; }
    else               { n = ry - 768; K = 128; Nw = 40;  W = W3; dh = bt3; }
    for (int k = t; k < K; k += 256) {
        float v;
        if (sage) v = (k < 128) ? Wl[(size_t)k * 128 + n] : Wr[(size_t)(k - 128) * 128 + n];
        else      v = (n < Nw) ? W[(size_t)k * Nw + n] : 0.f;
        dh[(size_t)n * K + k] = f2b(v);
    }
}

// ---------- MFMA GEMM: bf16 A and B, both DMA-staged via LDS ----------
// mode 0: relu(acc+bias) -> bf16 store; mode 2: acc+bias -> fp32, cols<colmax
template<int NT, int NCH, int AX>
__global__ __launch_bounds__(256, 5) void k_gemm2(
    const ushort* __restrict__ A, int K,
    const ushort* __restrict__ Bt,
    int M, int mode,
    const float* __restrict__ bias,
    float* __restrict__ Cf, int ldc,
    ushort* __restrict__ Ch, int ldch,
    int colmax)
{
    constexpr int COLS = NT * 16;
    constexpr int HOPU = 8 * COLS;       // B 16B-units per 64-k half (1 plane)
    constexpr int KTOT = NCH * 128;

    __shared__ __align__(16) ushort S[16384];   // 32 KB union
    ushort* Bs = S;
    ushort* As = S + 8192;

    const int lane = threadIdx.x & 63;
    const int wave = threadIdx.x >> 6;
    const int quad = lane >> 4;
    const int ln15 = lane & 15;
    const int brow = AX ? blockIdx.y : blockIdx.x;
    const int bcol = AX ? blockIdx.x : blockIdx.y;
    const int row0 = brow * 128 + wave * 32;
    const int col0 = bcol * COLS;
    const int Rbase = brow * 128;

    auto stageB = [&](int c, int h) {
        for (int u0 = wave * 64; u0 < HOPU; u0 += 256) {
            int u  = u0 + lane;
            int kq  = u / COLS;
            int col = u - kq * COLS;
            int kk  = c * 128 + h * 64 + kq * 8;
            const ushort* gp = Bt + (size_t)(col0 + col) * KTOT + kk;
            async_copy16(gp, (char*)Bs + (size_t)u0 * 16);
        }
    };
    auto stageA = [&](int c, int h) {
        #pragma unroll
        for (int i = 0; i < 4; ++i) {
            int u0 = (wave * 4 + i) * 64;
            int u  = u0 + lane;
            int row = u >> 3;
            int s   = u & 7;
            int sg  = s ^ (row & 7);
            int rr = Rbase + row; if (rr > M - 1) rr = M - 1;
            int kk = c * 128 + h * 64 + sg * 8;
            const ushort* gp = A + (size_t)rr * K + kk;
            async_copy16(gp, (char*)As + (size_t)u0 * 16);
        }
    };
    auto afrag = [&](int jj, int mt) -> s8v {
        int r = wave * 32 + mt * 16 + ln15;
        int sg = jj * 4 + quad;
        int unit = r * 8 + (sg ^ (r & 7));
        return *(const s8v*)(As + (size_t)unit * 8);
    };

    f4v acc[2][NT] = {};

    auto compute = [&](int jj) {
        s8v a0 = afrag(jj, 0);
        s8v a1 = afrag(jj, 1);
        #pragma unroll
        for (int t = 0; t < NT; ++t) {
            int ub = (jj * 4 + quad) * COLS + t * 16 + ln15;
            s8v b = *(const s8v*)(Bs + (size_t)ub * 8);
            acc[0][t] = __builtin_amdgcn_mfma_f32_16x16x32_bf16(a0, b, acc[0][t], 0, 0, 0);
            acc[1][t] = __builtin_amdgcn_mfma_f32_16x16x32_bf16(a1, b, acc[1][t], 0, 0, 0);
        }
    };

    stageB(0, 0); stageA(0, 0);
    __syncthreads();

    #pragma unroll
    for (int ph = 0; ph < NCH; ++ph) {
        #pragma unroll
        for (int h = 0; h < 2; ++h) {
            compute(0); compute(1);
            if (!(ph == NCH - 1 && h == 1)) {
                __syncthreads();
                int nc = ph, nh = h + 1;
                if (nh == 2) { nh = 0; ++nc; }
                stageB(nc, nh); stageA(nc, nh);
                __syncthreads();
            }
        }
    }

    if (NT == 8 && mode == 0) {
        __syncthreads();                          // staging LDS free now
        ushort* Lp = S + wave * 2176;             // wave-private quarter
        #pragma unroll
        for (int mt = 0; mt < 2; ++mt) {
            #pragma unroll
            for (int t = 0; t < NT; ++t) {
                int cc = col0 + t * 16 + ln15;
                #pragma unroll
                for (int r = 0; r < 4; ++r) {
                    float v = acc[mt][t][r] + bias[cc];
                    v = v > 0.f ? v : 0.f;
                    Lp[(quad * 4 + r) * LDSW + t * 16 + ln15] = f2b(v);
                }
            }
            int cb = (lane & 31) * 4;
            #pragma unroll
            for (int it = 0; it < 8; ++it) {
                int row2 = it * 2 + (lane >> 5);
                int rr = row0 + mt * 16 + row2;
                uint2 v = *(uint2*)(Lp + row2 * LDSW + cb);
                if (rr < M)
                    *(uint2*)(Ch + (size_t)rr * ldch + col0 + cb) = v;
            }
        }
    } else {
        #pragma unroll
        for (int t = 0; t < NT; ++t) {
            int cc = col0 + t * 16 + ln15;
            #pragma unroll
            for (int mt = 0; mt < 2; ++mt) {
                #pragma unroll
                for (int r = 0; r < 4; ++r) {
                    int rr = row0 + mt * 16 + quad * 4 + r;
                    if (rr < M && cc < colmax)
                        Cf[(size_t)rr * ldc + cc] = acc[mt][t][r] + bias[cc];
                }
            }
        }
    }
}

// ---------- merged producer GEMMs: z=0 GAT, z=1 GCN, z=2 SAGE ----------
// launch_bounds(256,3): keeps z0+z1 L2-resident hand-off (R14 lesson).
__global__ __launch_bounds__(256, 3) void k_gemm_prod(
    const ushort* __restrict__ tgb, const ushort* __restrict__ tcb,
    const ushort* __restrict__ tsb, const ushort* __restrict__ xb,
    const ushort* __restrict__ btg, const ushort* __restrict__ btc,
    const ushort* __restrict__ btsg,
    const float* __restrict__ bg, const float* __restrict__ bc,
    const float* __restrict__ bsl,
    float* __restrict__ pS, float* __restrict__ pQ,   // [NBLK][C3] partials
    ushort* __restrict__ hch)
{
    constexpr int COLS = 128;
    constexpr int HOPU = 8 * COLS;               // 1024 units per half
    __shared__ __align__(16) ushort S[16384];    // 32 KB union
    ushort* Bs = S;
    ushort* As = S + 8192;
    float* red = (float*)(S + 14336);            // 256 floats (dead As region)

    const int z = blockIdx.z;
    const ushort* A1 = (z == 0) ? tgb : (z == 1) ? tcb : tsb;
    const ushort* Bt = (z == 0) ? btg : (z == 1) ? btc : btsg;
    const float*  bias = (z == 0) ? bg : (z == 1) ? bc : bsl;
    const int nch = (z == 2) ? 2 : 1;
    const int ktot = nch * 128;

    const int lane = threadIdx.x & 63;
    const int wave = threadIdx.x >> 6;
    const int quad = lane >> 4;
    const int ln15 = lane & 15;
    const int row0 = blockIdx.x * 128 + wave * 32;
    const int Rbase = blockIdx.x * 128;

    auto stageB = [&](int c, int h) {
        for (int u0 = wave * 64; u0 < HOPU; u0 += 256) {
            int u  = u0 + lane;
            int kq  = u / COLS;
            int col = u - kq * COLS;
            int kk  = c * 128 + h * 64 + kq * 8;
            const ushort* gp = Bt + (size_t)col * ktot + kk;
            async_copy16(gp, (char*)Bs + (size_t)u0 * 16);
        }
    };
    auto stageA = [&](int c, int h) {
        #pragma unroll
        for (int i = 0; i < 4; ++i) {
            int u0 = (wave * 4 + i) * 64;
            int u  = u0 + lane;
            int row = u >> 3;
            int s   = u & 7;
            int sg  = s ^ (row & 7);
            int rr = Rbase + row; if (rr > NN - 1) rr = NN - 1;
            int kk = c * 128 + h * 64 + sg * 8;
            const ushort* gp = (kk < 128) ? (A1 + (size_t)rr * 128 + kk)
                                          : (xb + (size_t)rr * 128 + (kk - 128));
            async_copy16(gp, (char*)As + (size_t)u0 * 16);
        }
    };
    auto afrag = [&](int jj, int mt) -> s8v {
        int r = wave * 32 + mt * 16 + ln15;
        int sg = jj * 4 + quad;
        int unit = r * 8 + (sg ^ (r & 7));
        return *(const s8v*)(As + (size_t)unit * 8);
    };

    f4v acc[2][8] = {};

    auto compute = [&](int jj) {
        s8v a0 = afrag(jj, 0);
        s8v a1 = afrag(jj, 1);
        #pragma unroll
        for (int t = 0; t < 8; ++t) {
            int ub = (jj * 4 + quad) * COLS + t * 16 + ln15;
            s8v b = *(const s8v*)(Bs + (size_t)ub * 8);
            acc[0][t] = __builtin_amdgcn_mfma_f32_16x16x32_bf16(a0, b, acc[0][t], 0, 0, 0);
            acc[1][t] = __builtin_amdgcn_mfma_f32_16x16x32_bf16(a1, b, acc[1][t], 0, 0, 0);
        }
    };

    stageB(0, 0); stageA(0, 0);
    __syncthreads();

    for (int ph = 0; ph < nch; ++ph) {
        for (int h = 0; h < 2; ++h) {
            compute(0); compute(1);
            if (!(ph == nch - 1 && h == 1)) {
                __syncthreads();
                int nc = ph, nh = h + 1;
                if (nh == 2) { nh = 0; ++nc; }
                stageB(nc, nh); stageA(nc, nh);
                __syncthreads();
            }
        }
    }

    // LDS-transpose epilogue + per-lane BN partials
    __syncthreads();
    if (threadIdx.x < 256) red[threadIdx.x] = 0.f;   // As dead; red disjoint from Lp
    ushort* Lp = S + wave * 2176;
    float sp[8] = {}, qp[8] = {};
    #pragma unroll
    for (int mt = 0; mt < 2; ++mt) {
        #pragma unroll
        for (int t = 0; t < 8; ++t) {
            #pragma unroll
            for (int r = 0; r < 4; ++r) {
                int rr = row0 + mt * 16 + quad * 4 + r;
                float v = acc[mt][t][r] + bias[t * 16 + ln15];
                Lp[(quad * 4 + r) * LDSW + t * 16 + ln15] = f2b(v);
                if (rr < NN) { sp[t] += v; qp[t] += v * v; }
            }
        }
        int cb = (lane & 31) * 4;
        #pragma unroll
        for (int it = 0; it < 8; ++it) {
            int row2 = it * 2 + (lane >> 5);
            int rr = row0 + mt * 16 + row2;
            uint2 v = *(uint2*)(Lp + row2 * LDSW + cb);
            if (rr < NN)
                *(uint2*)(hch + (size_t)rr * C3 + z * 128 + cb) = v;
        }
    }
    // cross-wave LDS reduce (no contended global atomics)
    __syncthreads();
    #pragma unroll
    for (int t = 0; t < 8; ++t) {
        float s = sp[t], q = qp[t];
        s += __shfl_xor(s, 16); s += __shfl_xor(s, 32);
        q += __shfl_xor(q, 16); q += __shfl_xor(q, 32);
        if (quad == 0) {
            atomicAdd(&red[t * 16 + ln15], s);          // LDS atomic
            atomicAdd(&red[128 + t * 16 + ln15], q);
        }
    }
    __syncthreads();
    if (threadIdx.x < 128) {
        size_t o = (size_t)blockIdx.x * C3 + z * 128 + threadIdx.x;
        pS[o] = red[threadIdx.x];
        pQ[o] = red[128 + threadIdx.x];
    }
}

// ---------- hierarchical exclusive scan over (degA[i]+1) ----------
__global__ __launch_bounds__(256) void k_scan_part(
    const int* __restrict__ degA, int* __restrict__ bsum)
{
    int t = threadIdx.x;
    int b0 = blockIdx.x * SC_ELEMS;
    int i0 = b0 + t * 2;
    int v0 = (i0 < NN)     ? degA[i0] + 1     : 0;
    int v1 = (i0 + 1 < NN) ? degA[i0 + 1] + 1 : 0;
    int s = v0 + v1;
    #pragma unroll
    for (int off = 32; off; off >>= 1) s += __shfl_down(s, off);
    __shared__ int ws[4];
    if ((t & 63) == 0) ws[t >> 6] = s;
    __syncthreads();
    if (t == 0) bsum[blockIdx.x] = ws[0] + ws[1] + ws[2] + ws[3];
}

__global__ __launch_bounds__(128) void k_scan_tops(
    const int* __restrict__ bsum, int* __restrict__ boffs)
{
    __shared__ int sh[128];
    int t = threadIdx.x;
    int v = (t < SC_BLKS) ? bsum[t] : 0;
    sh[t] = v;
    __syncthreads();
    for (int off = 1; off < 128; off <<= 1) {
        int u = (t >= off) ? sh[t - off] : 0;
        __syncthreads();
        sh[t] += u;
        __syncthreads();
    }
    if (t < SC_BLKS) boffs[t] = sh[t] - v;   // exclusive
    if (t == SC_BLKS - 1) boffs[SC_BLKS] = sh[t];
}

__global__ __launch_bounds__(256) void k_scan_apply(
    const int* __restrict__ degA, const int* __restrict__ boffs,
    int* __restrict__ offs, int* __restrict__ cursor,
    float* __restrict__ dinv)
{
    __shared__ int sh[256];
    int t = threadIdx.x;
    int b0 = blockIdx.x * SC_ELEMS;
    int i0 = b0 + t * 2;
    int v0 = (i0 < NN)     ? degA[i0] + 1     : 0;
    int v1 = (i0 + 1 < NN) ? degA[i0 + 1] + 1 : 0;
    int pair = v0 + v1;
    sh[t] = pair;
    __syncthreads();
    for (int off = 1; off < 256; off <<= 1) {
        int u = (t >= off) ? sh[t - off] : 0;
        __syncthreads();
        sh[t] += u;
        __syncthreads();
    }
    int excl = sh[t] - pair + boffs[blockIdx.x];
    if (i0 < NN) {
        offs[i0] = excl; cursor[i0] = excl;
        dinv[i0] = rsqrtf((float)v0);
    }
    if (i0 + 1 < NN) {
        offs[i0 + 1] = excl + v0; cursor[i0 + 1] = excl + v0;
        dinv[i0 + 1] = rsqrtf((float)v1);
    }
    if (blockIdx.x == SC_BLKS - 1 && t == 255) offs[NN] = excl + pair;
}

// ---------- CSR fill: store SRC directly (self-slots store d) ----------
__global__ void k_csr_fill(const int* __restrict__ src, const int* __restrict__ dst,
                           int* __restrict__ cursor, int* __restrict__ esrc)
{
    int gid = blockIdx.x * blockDim.x + threadIdx.x;
    if (gid >= EE + NN) return;
    int d, s;
    if (gid < EE) { d = dst[gid]; s = src[gid]; }
    else          { d = gid - EE; s = d; }
    int slot = atomicAdd(&cursor[d], 1);
    esrc[slot] = s;
}

// ---------- CSR gather: packed-weight shuffles + 2x unrolled edge loop ----------
__global__ __launch_bounds__(256) void k_gather(
    const int* __restrict__ esrc, const int* __restrict__ offs,
    const float* __restrict__ a_s, const float* __restrict__ a_d,
    const float* __restrict__ dinv,
    const ushort* __restrict__ xb,
    ushort* __restrict__ tgb, ushort* __restrict__ tcb,
    ushort* __restrict__ tsb)
{
    int d = blockIdx.x * 4 + (threadIdx.x >> 6);
    if (d >= NN) return;
    int lane = threadIdx.x & 63;
    int beg = offs[d], end = offs[d + 1];
    float ad = a_d[d], dd = dinv[d];

    int idx0 = beg + lane;
    bool v0 = idx0 < end;
    int s0 = d; float e0 = 0.f, wc0 = 0.f;
    if (v0) {
        s0 = esrc[idx0];
        float e = a_s[s0] + ad;
        e0 = (e > 0.f) ? e : 0.2f * e;
        wc0 = dinv[s0] * dd;
    }
    float m = v0 ? e0 : -3.0e38f;
    for (int base = beg + 64; base < end; base += 64) {
        int idx = base + lane;
        if (idx < end) {
            int s = esrc[idx];
            float e = a_s[s] + ad;
            e = (e > 0.f) ? e : 0.2f * e;
            m = fmaxf(m, e);
        }
    }
    #pragma unroll
    for (int off = 1; off < 64; off <<= 1) m = fmaxf(m, __shfl_xor(m, off));
    float ex0 = v0 ? expf(e0 - m) : 0.f;
    float den = ex0;
    for (int base = beg + 64; base < end; base += 64) {
        int idx = base + lane;
        if (idx < end) {
            int s = esrc[idx];
            float e = a_s[s] + ad;
            e = (e > 0.f) ? e : 0.2f * e;
            den += expf(e - m);
        }
    }
    #pragma unroll
    for (int off = 1; off < 64; off <<= 1) den += __shfl_xor(den, off);
    float rden = 1.f / den;

    float2 tg = {0.f, 0.f}, tc = {0.f, 0.f}, ts = {0.f, 0.f};
    int c = lane * 2;
    {
        float wg = ex0 * rden;      // 0 when invalid
        uint pw0 = (uint)f2b(wg) | ((uint)f2b(wc0) << 16);
        int cnt = end - beg; if (cnt > 64) cnt = 64;
        int j = 0;
        // unroll x2: two independent shuffle->load chains in flight
        for (; j + 1 < cnt; j += 2) {
            int  sa  = __shfl(s0, j);
            uint pa  = __shfl(pw0, j);
            int  sb  = __shfl(s0, j + 1);
            uint pb  = __shfl(pw0, j + 1);
            ushort2 xa = *(const ushort2*)(xb + (size_t)sa * 128 + c);
            ushort2 xc = *(const ushort2*)(xb + (size_t)sb * 128 + c);
            float wga = b2f((ushort)(pa & 0xffffu)), wca = b2f((ushort)(pa >> 16));
            float ax = b2f(xa.x), ay = b2f(xa.y);
            tg.x += wga * ax; tg.y += wga * ay;
            tc.x += wca * ax; tc.y += wca * ay;
            ts.x += ax;       ts.y += ay;
            float wgb = b2f((ushort)(pb & 0xffffu)), wcb = b2f((ushort)(pb >> 16));
            float bx = b2f(xc.x), by = b2f(xc.y);
            tg.x += wgb * bx; tg.y += wgb * by;
            tc.x += wcb * bx; tc.y += wcb * by;
            ts.x += bx;       ts.y += by;
        }
        if (j < cnt) {
            int  sa = __shfl(s0, j);
            uint pa = __shfl(pw0, j);
            ushort2 xa = *(const ushort2*)(xb + (size_t)sa * 128 + c);
            float wga = b2f((ushort)(pa & 0xffffu)), wca = b2f((ushort)(pa >> 16));
            float ax = b2f(xa.x), ay = b2f(xa.y);
            tg.x += wga * ax; tg.y += wga * ay;
            tc.x += wca * ax; tc.y += wca * ay;
            ts.x += ax;       ts.y += ay;
        }
    }
    for (int base = beg + 64; base < end; base += 64) {
        int idx = base + lane;
        int s = d; uint pw = 0;
        if (idx < end) {
            s = esrc[idx];
            float e = a_s[s] + ad;
            e = (e > 0.f) ? e : 0.2f * e;
            float wg = expf(e - m) * rden;
            float wc = dinv[s] * dd;
            pw = (uint)f2b(wg) | ((uint)f2b(wc) << 16);
        }
        int cnt = end - base; if (cnt > 64) cnt = 64;
        int j = 0;
        for (; j + 1 < cnt; j += 2) {
            int  sa  = __shfl(s, j);
            uint pa  = __shfl(pw, j);
            int  sb  = __shfl(s, j + 1);
            uint pb  = __shfl(pw, j + 1);
            ushort2 xa = *(const ushort2*)(xb + (size_t)sa * 128 + c);
            ushort2 xc = *(const ushort2*)(xb + (size_t)sb * 128 + c);
            float wga = b2f((ushort)(pa & 0xffffu)), wca = b2f((ushort)(pa >> 16));
            float ax = b2f(xa.x), ay = b2f(xa.y);
            tg.x += wga * ax; tg.y += wga * ay;
            tc.x += wca * ax; tc.y += wca * ay;
            ts.x += ax;       ts.y += ay;
            float wgb = b2f((ushort)(pb & 0xffffu)), wcb = b2f((ushort)(pb >> 16));
            float bx = b2f(xc.x), by = b2f(xc.y);
            tg.x += wgb * bx; tg.y += wgb * by;
            tc.x += wcb * bx; tc.y += wcb * by;
            ts.x += bx;       ts.y += by;
        }
        if (j < cnt) {
            int  sa = __shfl(s, j);
            uint pa = __shfl(pw, j);
            ushort2 xa = *(const ushort2*)(xb + (size_t)sa * 128 + c);
            float wga = b2f((ushort)(pa & 0xffffu)), wca = b2f((ushort)(pa >> 16));
            float ax = b2f(xa.x), ay = b2f(xa.y);
            tg.x += wga * ax; tg.y += wga * ay;
            tc.x += wca * ax; tc.y += wca * ay;
            ts.x += ax;       ts.y += ay;
        }
    }
    ushort2 xdu = *(const ushort2*)(xb + (size_t)d * 128 + c);
    ts.x -= b2f(xdu.x); ts.y -= b2f(xdu.y);
    int cs = (end - beg) - 1;
    float rc = 1.f / (float)(cs > 1 ? cs : 1);
    ts.x *= rc; ts.y *= rc;

    size_t row = (size_t)d * 128 + c;
    { ushort2 u; u.x = f2b(tg.x); u.y = f2b(tg.y); *(ushort2*)(tgb + row) = u; }
    { ushort2 u; u.x = f2b(tc.x); u.y = f2b(tc.y); *(ushort2*)(tcb + row) = u; }
    { ushort2 u; u.x = f2b(ts.x); u.y = f2b(ts.y); *(ushort2*)(tsb + row) = u; }
}

// ---------- BN final: reduce per-block partials, fold gamma/beta ----------
__global__ void k_bn_final(const float* __restrict__ pS, const float* __restrict__ pQ,
                           const float* __restrict__ gamma, const float* __restrict__ beta,
                           float* __restrict__ scale, float* __restrict__ shift)
{
    int j = threadIdx.x;
    if (j >= C3) return;
    float s = 0.f, q = 0.f;
    for (int r = 0; r < NBLK; ++r) {
        s += pS[(size_t)r * C3 + j];
        q += pQ[(size_t)r * C3 + j];
    }
    const float rn = 1.f / (float)NN;
    float mu  = s * rn;
    float var = q * rn - mu * mu;
    float sc  = gamma[j] * rsqrtf(var + 1e-5f);
    scale[j] = sc;
    shift[j] = beta[j] - mu * sc;
}

// ---------- in-place BN+relu of hcat (8 elems/thread, 16B ld/st) ----------
__global__ __launch_bounds__(256) void k_bnrelu(
    ushort* __restrict__ hch,
    const float* __restrict__ scale, const float* __restrict__ shift)
{
    int p = blockIdx.x * blockDim.x + threadIdx.x;
    if (p >= NN * 48) return;
    int cidx = (p % 48) * 8;
    size_t o = (size_t)p * 8;
    uint4 w = *(uint4*)(hch + o);
    uint wr[4] = {w.x, w.y, w.z, w.w};
    uint out[4];
    #pragma unroll
    for (int i = 0; i < 4; ++i) {
        ushort u0 = (ushort)(wr[i] & 0xffffu), u1 = (ushort)(wr[i] >> 16);
        int cc = cidx + i * 2;
        float v0 = b2f(u0) * scale[cc]     + shift[cc];
        float v1 = b2f(u1) * scale[cc + 1] + shift[cc + 1];
        v0 = v0 > 0.f ? v0 : 0.f;
        v1 = v1 > 0.f ? v1 : 0.f;
        out[i] = (uint)f2b(v0) | ((uint)f2b(v1) << 16);
    }
    uint4 r; r.x = out[0]; r.y = out[1]; r.z = out[2]; r.w = out[3];
    *(uint4*)(hch + o) = r;
}

extern "C" void kernel_launch(void* const* d_in, const int* in_sizes, int n_in,
                              void* d_out, int out_size, void* d_ws, size_t ws_size,
                              hipStream_t stream) {
    const float* x        = (const float*)d_in[0];
    const int*   ei       = (const int*)d_in[1];
    const float* W_gat    = (const float*)d_in[2];
    const float* att_src  = (const float*)d_in[3];
    const float* att_dst  = (const float*)d_in[4];
    const float* b_gat    = (const float*)d_in[5];
    const float* W_gcn    = (const float*)d_in[6];
    const float* b_gcn    = (const float*)d_in[7];
    const float* W_sage_l = (const float*)d_in[8];
    const float* b_sage_l = (const float*)d_in[9];
    const float* W_sage_r = (const float*)d_in[10];
    const float* W1       = (const float*)d_in[11];
    const float* b1       = (const float*)d_in[12];
    const float* W2       = (const float*)d_in[13];
    const float* b2       = (const float*)d_in[14];
    const float* W3       = (const float*)d_in[15];
    const float* b3       = (const float*)d_in[16];
    const float* gamma    = (const float*)d_in[17];
    const float* beta     = (const float*)d_in[18];

    const int* e_src = ei;
    const int* e_dst = ei + EE;

    // ---- workspace layout (16B-aligned) ----
    char* base = (char*)d_ws;
    size_t o = 0;
    ushort* hch  = (ushort*)(base + o); o += (size_t)NN * C3 * 2;
    ushort* tgb  = (ushort*)(base + o); o += (size_t)NN * 128 * 2;    // a1 overlay
    ushort* tcb  = (ushort*)(base + o); o += (size_t)NN * 128 * 2;
    ushort* tsb  = (ushort*)(base + o); o += (size_t)NN * 128 * 2;    // a2 overlay
    ushort* xb   = (ushort*)(base + o); o += (size_t)NN * 128 * 2;
    int*    esrc = (int*)(base + o);    o += (size_t)(EE + NN) * 4;
    int*    offs = (int*)(base + o);    o += (size_t)(NN + 16) * 4;
    int*    cursor=(int*)(base + o);    o += (size_t)NN * 4;
    float*  as_  = (float*)(base + o);  o += (size_t)NN * 4;
    float*  ad_  = (float*)(base + o);  o += (size_t)NN * 4;
    float*  dinv = (float*)(base + o);  o += (size_t)NN * 4;
    int*    bsum = (int*)(base + o);    o += 256 * 4;
    int*    boffs= (int*)(base + o);    o += 256 * 4;
    // --- zero-init region: degA only ---
    int*    degA = (int*)(base + o);    o += (size_t)NN * 4;
    // --- end zero region ---
    float*  pS   = (float*)(base + o);  o += (size_t)NBLK * C3 * 4;   // written fully
    float*  pQ   = (float*)(base + o);  o += (size_t)NBLK * C3 * 4;
    float*  scale= (float*)(base + o);  o += C3 * 4;
    float*  shift= (float*)(base + o);  o += C3 * 4;
    float*  w_as = (float*)(base + o);  o += 128 * 4;
    float*  w_ad = (float*)(base + o);  o += 128 * 4;
    ushort* btg  = (ushort*)(base + o); o += 128 * 128 * 2;
    ushort* btc  = (ushort*)(base + o); o += 128 * 128 * 2;
    ushort* btsg = (ushort*)(base + o); o += 128 * 256 * 2;
    ushort* bt1  = (ushort*)(base + o); o += 256 * 384 * 2;
    ushort* bt2  = (ushort*)(base + o); o += 128 * 256 * 2;
    ushort* bt3  = (ushort*)(base + o); o += 48 * 128 * 2;
    // overlays (temporally disjoint)
    ushort* a1 = tgb;                        // NN*256 ushorts (tgb+tcb)
    ushort* a2 = tsb;                        // NN*128

    hipMemsetAsync(degA, 0, (size_t)NN * 4, stream);

    // ---- weight prep ----
    k_splitw_all<<<817, 256, 0, stream>>>(W_gat, W_gcn, W_sage_l, W_sage_r, W1, W2, W3,
        att_src, att_dst, w_as, w_ad, btg, btc, btsg, bt1, bt2, bt3);
    // split x + attention dots + degree histogram (merged)
    k_split_x_att<<<SPLIT_BLKS + HIST_BLKS, 256, 0, stream>>>(
        x, w_as, w_ad, e_dst, degA, xb, as_, ad_);

    // ---- CSR build ----
    k_scan_part<<<SC_BLKS, 256, 0, stream>>>(degA, bsum);
    k_scan_tops<<<1, 128, 0, stream>>>(bsum, boffs);
    k_scan_apply<<<SC_BLKS, 256, 0, stream>>>(degA, boffs, offs, cursor, dinv);
    k_csr_fill<<<(EE + NN + 255) / 256, 256, 0, stream>>>(e_src, e_dst, cursor, esrc);

    // ---- gather (bf16 x, direct-src CSR, packed-weight shuffles, 2x unroll) ----
    k_gather<<<(NN + 3) / 4, 256, 0, stream>>>(
        esrc, offs, as_, ad_, dinv, xb, tgb, tcb, tsb);

    // ---- producers: one launch, privatized BN partials ----
    k_gemm_prod<<<dim3(NBLK, 1, 3), 256, 0, stream>>>(
        tgb, tcb, tsb, xb, btg, btc, btsg,
        b_gat, b_gcn, b_sage_l, pS, pQ, hch);

    // ---- BN fold (partials reduce) + standalone BN+relu pass ----
    k_bn_final<<<1, C3, 0, stream>>>(pS, pQ, gamma, beta, scale, shift);
    k_bnrelu<<<(NN * 48 + 255) / 256, 256, 0, stream>>>(hch, scale, shift);

    // ---- MLP ----
    k_gemm2<8, 3, 1><<<dim3(2, NBLK), 256, 0, stream>>>(
        hch, 384, bt1, NN, 0, b1, nullptr, 0, a1, 256, 256);
    k_gemm2<8, 2, 0><<<dim3(NBLK, 1), 256, 0, stream>>>(
        a1, 256, bt2, NN, 0, b2, nullptr, 0, a2, 128, 128);
    k_gemm2<3, 1, 0><<<dim3(NBLK, 1), 256, 0, stream>>>(
        a2, 128, bt3, NN, 2, b3, (float*)d_out, NOUT, nullptr, 0, NOUT);
}

// Round 21
// 391.632 us; speedup vs baseline: 1.1201x; 1.0146x over previous
//
#include <hip/hip_runtime.h>
#include <cstdint>
#include <cstddef>

#define NN   50000
#define FIN  128
#define HD   128
#define EE   800000
#define C3   384   // 3*H
#define NOUT 40

#define SC_ELEMS 512
#define SC_BLKS  ((NN + SC_ELEMS - 1) / SC_ELEMS)   // 98
#define NBLK ((NN + 127) / 128)                     // 391 row-blocks

#define SPLIT_BLKS ((NN + 3) / 4)                   // 12500
#define HIST_BLKS  ((EE + 255) / 256)               // 3125

#define LDSW 132   // padded epilogue LDS row stride (ushorts)

typedef __attribute__((ext_vector_type(8))) short s8v;   // 8 x bf16 (4 VGPR)
typedef __attribute__((ext_vector_type(4))) float f4v;   // MFMA acc

typedef const __attribute__((address_space(1))) unsigned int* guintp;
typedef __attribute__((address_space(3))) unsigned int* luintp;

static __device__ __forceinline__ void async_copy16(const void* g, void* l) {
    __builtin_amdgcn_global_load_lds((guintp)g, (luintp)l, 16, 0, 0);
}

// ---------- bf16 helpers ----------
static __device__ __forceinline__ float b2f(ushort u) {
    return __uint_as_float((unsigned)u << 16);
}
static __device__ __forceinline__ ushort f2b(float v) {
    unsigned u = __float_as_uint(v);
    unsigned r = u + 0x7fffu + ((u >> 16) & 1u);
    return (ushort)(r >> 16);
}

// ---------- merged: x -> bf16, attention dots, AND dst-degree histogram ----------
__global__ __launch_bounds__(256) void k_split_x_att(
    const float* __restrict__ x,
    const float* __restrict__ w_as, const float* __restrict__ w_ad,
    const int* __restrict__ e_dst, int* __restrict__ degA,
    ushort* __restrict__ xb,
    float* __restrict__ a_s, float* __restrict__ a_d)
{
    if (blockIdx.x >= SPLIT_BLKS) {
        int gid = (blockIdx.x - SPLIT_BLKS) * 256 + threadIdx.x;
        if (gid < EE) atomicAdd(&degA[e_dst[gid]], 1);
        return;
    }
    int node = blockIdx.x * 4 + (threadIdx.x >> 6);
    if (node >= NN) return;
    int lane = threadIdx.x & 63;
    size_t o = (size_t)node * 128 + lane * 2;
    float2 v  = *(const float2*)(x + o);
    { ushort2 u; u.x = f2b(v.x); u.y = f2b(v.y); *(ushort2*)(xb + o) = u; }
    float2 w1 = *(const float2*)(w_as + lane * 2);
    float2 w2 = *(const float2*)(w_ad + lane * 2);
    float s1 = v.x * w1.x + v.y * w1.y;
    float s2 = v.x * w2.x + v.y * w2.y;
    #pragma unroll
    for (int off = 32; off; off >>= 1) {
        s1 += __shfl_down(s1, off);
        s2 += __shfl_down(s2, off);
    }
    if (lane == 0) { a_s[node] = s1; a_d[node] = s2; }
}

// ---------- weight transposes (single bf16 plane) + att fold ----------
__global__ void k_splitw_all(
    const float* __restrict__ Wg, const float* __restrict__ Wc,
    const float* __restrict__ Wl, const float* __restrict__ Wr,
    const float* __restrict__ W1, const float* __restrict__ W2,
    const float* __restrict__ W3,
    const float* __restrict__ asv, const float* __restrict__ adv,
    float* __restrict__ w_as, float* __restrict__ w_ad,
    ushort* __restrict__ btg, ushort* __restrict__ btc,
    ushort* __restrict__ btsg,
    ushort* __restrict__ bt1, ushort* __restrict__ bt2,
    ushort* __restrict__ bt3)
{
    int ry = blockIdx.x;
    int t = threadIdx.x;
    if (ry == 816) {
        if (t < 128) {
            float s1 = 0.f, s2 = 0.f;
            for (int j = 0; j < 128; ++j) {
                float w = Wg[t * 128 + j];
                s1 += w * asv[j];
                s2 += w * adv[j];
            }
            w_as[t] = s1; w_ad[t] = s2;
        }
        return;
    }
    const float* W = nullptr; ushort* dh; int K, Nw, n;
    bool sage = false;
    if (ry < 128)      { n = ry;       K = 128; Nw = 128; W = Wg; dh = btg; }
    else if (ry < 256) { n = ry - 128; K = 128; Nw = 128; W = Wc; dh = btc; }
    else if (ry < 384) { n = ry - 256; K = 256; Nw = 128; sage = true; dh = btsg; }
    else if (ry < 640) { n = ry - 384; K = 384; Nw = 256; W = W1; dh = bt1; }
    else if (ry < 768) { n = ry - 640; K = 256; Nw = 128; W = W2; dh = bt2; }
    else               { n = ry - 768; K = 128; Nw = 40;  W = W3; dh = bt3; }
    for (int k = t; k < K; k += 256) {
        float v;
        if (sage) v = (k < 128) ? Wl[(size_t)k * 128 + n] : Wr[(size_t)(k - 128) * 128 + n];
        else      v = (n < Nw) ? W[(size_t)k * Nw + n] : 0.f;
        dh[(size_t)n * K + k] = f2b(v);
    }
}

// ---------- MFMA GEMM: bf16 A and B, both DMA-staged via LDS ----------
// mode 0: relu(acc+bias) -> bf16 store; mode 2: acc+bias -> fp32, cols<colmax
template<int NT, int NCH, int AX>
__global__ __launch_bounds__(256, 5) void k_gemm2(
    const ushort* __restrict__ A, int K,
    const ushort* __restrict__ Bt,
    int M, int mode,
    const float* __restrict__ bias,
    float* __restrict__ Cf, int ldc,
    ushort* __restrict__ Ch, int ldch,
    int colmax)
{
    constexpr int COLS = NT * 16;
    constexpr int HOPU = 8 * COLS;       // B 16B-units per 64-k half (1 plane)
    constexpr int KTOT = NCH * 128;

    __shared__ __align__(16) ushort S[16384];   // 32 KB union
    ushort* Bs = S;
    ushort* As = S + 8192;

    const int lane = threadIdx.x & 63;
    const int wave = threadIdx.x >> 6;
    const int quad = lane >> 4;
    const int ln15 = lane & 15;
    const int brow = AX ? blockIdx.y : blockIdx.x;
    const int bcol = AX ? blockIdx.x : blockIdx.y;
    const int row0 = brow * 128 + wave * 32;
    const int col0 = bcol * COLS;
    const int Rbase = brow * 128;

    auto stageB = [&](int c, int h) {
        for (int u0 = wave * 64; u0 < HOPU; u0 += 256) {
            int u  = u0 + lane;
            int kq  = u / COLS;
            int col = u - kq * COLS;
            int kk  = c * 128 + h * 64 + kq * 8;
            const ushort* gp = Bt + (size_t)(col0 + col) * KTOT + kk;
            async_copy16(gp, (char*)Bs + (size_t)u0 * 16);
        }
    };
    auto stageA = [&](int c, int h) {
        #pragma unroll
        for (int i = 0; i < 4; ++i) {
            int u0 = (wave * 4 + i) * 64;
            int u  = u0 + lane;
            int row = u >> 3;
            int s   = u & 7;
            int sg  = s ^ (row & 7);
            int rr = Rbase + row; if (rr > M - 1) rr = M - 1;
            int kk = c * 128 + h * 64 + sg * 8;
            const ushort* gp = A + (size_t)rr * K + kk;
            async_copy16(gp, (char*)As + (size_t)u0 * 16);
        }
    };
    auto afrag = [&](int jj, int mt) -> s8v {
        int r = wave * 32 + mt * 16 + ln15;
        int sg = jj * 4 + quad;
        int unit = r * 8 + (sg ^ (r & 7));
        return *(const s8v*)(As + (size_t)unit * 8);
    };

    f4v acc[2][NT] = {};

    auto compute = [&](int jj) {
        s8v a0 = afrag(jj, 0);
        s8v a1 = afrag(jj, 1);
        #pragma unroll
        for (int t = 0; t < NT; ++t) {
            int ub = (jj * 4 + quad) * COLS + t * 16 + ln15;
            s8v b = *(const s8v*)(Bs + (size_t)ub * 8);
            acc[0][t] = __builtin_amdgcn_mfma_f32_16x16x32_bf16(a0, b, acc[0][t], 0, 0, 0);
            acc[1][t] = __builtin_amdgcn_mfma_f32_16x16x32_bf16(a1, b, acc[1][t], 0, 0, 0);
        }
    };

    stageB(0, 0); stageA(0, 0);
    __syncthreads();

    #pragma unroll
    for (int ph = 0; ph < NCH; ++ph) {
        #pragma unroll
        for (int h = 0; h < 2; ++h) {
            compute(0); compute(1);
            if (!(ph == NCH - 1 && h == 1)) {
                __syncthreads();
                int nc = ph, nh = h + 1;
                if (nh == 2) { nh = 0; ++nc; }
                stageB(nc, nh); stageA(nc, nh);
                __syncthreads();
            }
        }
    }

    if (NT == 8 && mode == 0) {
        __syncthreads();                          // staging LDS free now
        ushort* Lp = S + wave * 2176;             // wave-private quarter
        #pragma unroll
        for (int mt = 0; mt < 2; ++mt) {
            #pragma unroll
            for (int t = 0; t < NT; ++t) {
                int cc = col0 + t * 16 + ln15;
                #pragma unroll
                for (int r = 0; r < 4; ++r) {
                    float v = acc[mt][t][r] + bias[cc];
                    v = v > 0.f ? v : 0.f;
                    Lp[(quad * 4 + r) * LDSW + t * 16 + ln15] = f2b(v);
                }
            }
            int cb = (lane & 31) * 4;
            #pragma unroll
            for (int it = 0; it < 8; ++it) {
                int row2 = it * 2 + (lane >> 5);
                int rr = row0 + mt * 16 + row2;
                uint2 v = *(uint2*)(Lp + row2 * LDSW + cb);
                if (rr < M)
                    *(uint2*)(Ch + (size_t)rr * ldch + col0 + cb) = v;
            }
        }
    } else {
        #pragma unroll
        for (int t = 0; t < NT; ++t) {
            int cc = col0 + t * 16 + ln15;
            #pragma unroll
            for (int mt = 0; mt < 2; ++mt) {
                #pragma unroll
                for (int r = 0; r < 4; ++r) {
                    int rr = row0 + mt * 16 + quad * 4 + r;
                    if (rr < M && cc < colmax)
                        Cf[(size_t)rr * ldc + cc] = acc[mt][t][r] + bias[cc];
                }
            }
        }
    }
}

// ---------- merged producer GEMMs: z=0 GAT, z=1 GCN, z=2 SAGE ----------
// launch_bounds(256,3): keeps z0+z1 L2-resident hand-off (R14 lesson).
__global__ __launch_bounds__(256, 3) void k_gemm_prod(
    const ushort* __restrict__ tgb, const ushort* __restrict__ tcb,
    const ushort* __restrict__ tsb, const ushort* __restrict__ xb,
    const ushort* __restrict__ btg, const ushort* __restrict__ btc,
    const ushort* __restrict__ btsg,
    const float* __restrict__ bg, const float* __restrict__ bc,
    const float* __restrict__ bsl,
    float* __restrict__ pS, float* __restrict__ pQ,   // [NBLK][C3] partials
    ushort* __restrict__ hch)
{
    constexpr int COLS = 128;
    constexpr int HOPU = 8 * COLS;               // 1024 units per half
    __shared__ __align__(16) ushort S[16384];    // 32 KB union
    ushort* Bs = S;
    ushort* As = S + 8192;
    float* red = (float*)(S + 14336);            // 256 floats (dead As region)

    const int z = blockIdx.z;
    const ushort* A1 = (z == 0) ? tgb : (z == 1) ? tcb : tsb;
    const ushort* Bt = (z == 0) ? btg : (z == 1) ? btc : btsg;
    const float*  bias = (z == 0) ? bg : (z == 1) ? bc : bsl;
    const int nch = (z == 2) ? 2 : 1;
    const int ktot = nch * 128;

    const int lane = threadIdx.x & 63;
    const int wave = threadIdx.x >> 6;
    const int quad = lane >> 4;
    const int ln15 = lane & 15;
    const int row0 = blockIdx.x * 128 + wave * 32;
    const int Rbase = blockIdx.x * 128;

    auto stageB = [&](int c, int h) {
        for (int u0 = wave * 64; u0 < HOPU; u0 += 256) {
            int u  = u0 + lane;
            int kq  = u / COLS;
            int col = u - kq * COLS;
            int kk  = c * 128 + h * 64 + kq * 8;
            const ushort* gp = Bt + (size_t)col * ktot + kk;
            async_copy16(gp, (char*)Bs + (size_t)u0 * 16);
        }
    };
    auto stageA = [&](int c, int h) {
        #pragma unroll
        for (int i = 0; i < 4; ++i) {
            int u0 = (wave * 4 + i) * 64;
            int u  = u0 + lane;
            int row = u >> 3;
            int s   = u & 7;
            int sg  = s ^ (row & 7);
            int rr = Rbase + row; if (rr > NN - 1) rr = NN - 1;
            int kk = c * 128 + h * 64 + sg * 8;
            const ushort* gp = (kk < 128) ? (A1 + (size_t)rr * 128 + kk)
                                          : (xb + (size_t)rr * 128 + (kk - 128));
            async_copy16(gp, (char*)As + (size_t)u0 * 16);
        }
    };
    auto afrag = [&](int jj, int mt) -> s8v {
        int r = wave * 32 + mt * 16 + ln15;
        int sg = jj * 4 + quad;
        int unit = r * 8 + (sg ^ (r & 7));
        return *(const s8v*)(As + (size_t)unit * 8);
    };

    f4v acc[2][8] = {};

    auto compute = [&](int jj) {
        s8v a0 = afrag(jj, 0);
        s8v a1 = afrag(jj, 1);
        #pragma unroll
        for (int t = 0; t < 8; ++t) {
            int ub = (jj * 4 + quad) * COLS + t * 16 + ln15;
            s8v b = *(const s8v*)(Bs + (size_t)ub * 8);
            acc[0][t] = __builtin_amdgcn_mfma_f32_16x16x32_bf16(a0, b, acc[0][t], 0, 0, 0);
            acc[1][t] = __builtin_amdgcn_mfma_f32_16x16x32_bf16(a1, b, acc[1][t], 0, 0, 0);
        }
    };

    stageB(0, 0); stageA(0, 0);
    __syncthreads();

    for (int ph = 0; ph < nch; ++ph) {
        for (int h = 0; h < 2; ++h) {
            compute(0); compute(1);
            if (!(ph == nch - 1 && h == 1)) {
                __syncthreads();
                int nc = ph, nh = h + 1;
                if (nh == 2) { nh = 0; ++nc; }
                stageB(nc, nh); stageA(nc, nh);
                __syncthreads();
            }
        }
    }

    // LDS-transpose epilogue + per-lane BN partials
    __syncthreads();
    if (threadIdx.x < 256) red[threadIdx.x] = 0.f;   // As dead; red disjoint from Lp
    ushort* Lp = S + wave * 2176;
    float sp[8] = {}, qp[8] = {};
    #pragma unroll
    for (int mt = 0; mt < 2; ++mt) {
        #pragma unroll
        for (int t = 0; t < 8; ++t) {
            #pragma unroll
            for (int r = 0; r < 4; ++r) {
                int rr = row0 + mt * 16 + quad * 4 + r;
                float v = acc[mt][t][r] + bias[t * 16 + ln15];
                Lp[(quad * 4 + r) * LDSW + t * 16 + ln15] = f2b(v);
                if (rr < NN) { sp[t] += v; qp[t] += v * v; }
            }
        }
        int cb = (lane & 31) * 4;
        #pragma unroll
        for (int it = 0; it < 8; ++it) {
            int row2 = it * 2 + (lane >> 5);
            int rr = row0 + mt * 16 + row2;
            uint2 v = *(uint2*)(Lp + row2 * LDSW + cb);
            if (rr < NN)
                *(uint2*)(hch + (size_t)rr * C3 + z * 128 + cb) = v;
        }
    }
    // cross-wave LDS reduce (no contended global atomics)
    __syncthreads();
    #pragma unroll
    for (int t = 0; t < 8; ++t) {
        float s = sp[t], q = qp[t];
        s += __shfl_xor(s, 16); s += __shfl_xor(s, 32);
        q += __shfl_xor(q, 16); q += __shfl_xor(q, 32);
        if (quad == 0) {
            atomicAdd(&red[t * 16 + ln15], s);          // LDS atomic
            atomicAdd(&red[128 + t * 16 + ln15], q);
        }
    }
    __syncthreads();
    if (threadIdx.x < 128) {
        size_t o = (size_t)blockIdx.x * C3 + z * 128 + threadIdx.x;
        pS[o] = red[threadIdx.x];
        pQ[o] = red[128 + threadIdx.x];
    }
}

// ---------- hierarchical exclusive scan over (degA[i]+1) ----------
__global__ __launch_bounds__(256) void k_scan_part(
    const int* __restrict__ degA, int* __restrict__ bsum)
{
    int t = threadIdx.x;
    int b0 = blockIdx.x * SC_ELEMS;
    int i0 = b0 + t * 2;
    int v0 = (i0 < NN)     ? degA[i0] + 1     : 0;
    int v1 = (i0 + 1 < NN) ? degA[i0 + 1] + 1 : 0;
    int s = v0 + v1;
    #pragma unroll
    for (int off = 32; off; off >>= 1) s += __shfl_down(s, off);
    __shared__ int ws[4];
    if ((t & 63) == 0) ws[t >> 6] = s;
    __syncthreads();
    if (t == 0) bsum[blockIdx.x] = ws[0] + ws[1] + ws[2] + ws[3];
}

__global__ __launch_bounds__(128) void k_scan_tops(
    const int* __restrict__ bsum, int* __restrict__ boffs)
{
    __shared__ int sh[128];
    int t = threadIdx.x;
    int v = (t < SC_BLKS) ? bsum[t] : 0;
    sh[t] = v;
    __syncthreads();
    for (int off = 1; off < 128; off <<= 1) {
        int u = (t >= off) ? sh[t - off] : 0;
        __syncthreads();
        sh[t] += u;
        __syncthreads();
    }
    if (t < SC_BLKS) boffs[t] = sh[t] - v;   // exclusive
    if (t == SC_BLKS - 1) boffs[SC_BLKS] = sh[t];
}

__global__ __launch_bounds__(256) void k_scan_apply(
    const int* __restrict__ degA, const int* __restrict__ boffs,
    int* __restrict__ offs, int* __restrict__ cursor,
    float* __restrict__ dinv)
{
    __shared__ int sh[256];
    int t = threadIdx.x;
    int b0 = blockIdx.x * SC_ELEMS;
    int i0 = b0 + t * 2;
    int v0 = (i0 < NN)     ? degA[i0] + 1     : 0;
    int v1 = (i0 + 1 < NN) ? degA[i0 + 1] + 1 : 0;
    int pair = v0 + v1;
    sh[t] = pair;
    __syncthreads();
    for (int off = 1; off < 256; off <<= 1) {
        int u = (t >= off) ? sh[t - off] : 0;
        __syncthreads();
        sh[t] += u;
        __syncthreads();
    }
    int excl = sh[t] - pair + boffs[blockIdx.x];
    if (i0 < NN) {
        offs[i0] = excl; cursor[i0] = excl;
        dinv[i0] = rsqrtf((float)v0);
    }
    if (i0 + 1 < NN) {
        offs[i0 + 1] = excl + v0; cursor[i0 + 1] = excl + v0;
        dinv[i0 + 1] = rsqrtf((float)v1);
    }
    if (blockIdx.x == SC_BLKS - 1 && t == 255) offs[NN] = excl + pair;
}

// ---------- CSR fill: store SRC as ushort (NN < 65536) ----------
// halves payload -> halves the cross-XCD partial-line writeback amplification
__global__ void k_csr_fill(const int* __restrict__ src, const int* __restrict__ dst,
                           int* __restrict__ cursor, ushort* __restrict__ esrc)
{
    int gid = blockIdx.x * blockDim.x + threadIdx.x;
    if (gid >= EE + NN) return;
    int d, s;
    if (gid < EE) { d = dst[gid]; s = src[gid]; }
    else          { d = gid - EE; s = d; }
    int slot = atomicAdd(&cursor[d], 1);
    esrc[slot] = (ushort)s;
}

// ---------- CSR gather: packed-weight shuffles + 2x unrolled edge loop ----------
__global__ __launch_bounds__(256) void k_gather(
    const ushort* __restrict__ esrc, const int* __restrict__ offs,
    const float* __restrict__ a_s, const float* __restrict__ a_d,
    const float* __restrict__ dinv,
    const ushort* __restrict__ xb,
    ushort* __restrict__ tgb, ushort* __restrict__ tcb,
    ushort* __restrict__ tsb)
{
    int d = blockIdx.x * 4 + (threadIdx.x >> 6);
    if (d >= NN) return;
    int lane = threadIdx.x & 63;
    int beg = offs[d], end = offs[d + 1];
    float ad = a_d[d], dd = dinv[d];

    int idx0 = beg + lane;
    bool v0 = idx0 < end;
    int s0 = d; float e0 = 0.f, wc0 = 0.f;
    if (v0) {
        s0 = esrc[idx0];
        float e = a_s[s0] + ad;
        e0 = (e > 0.f) ? e : 0.2f * e;
        wc0 = dinv[s0] * dd;
    }
    float m = v0 ? e0 : -3.0e38f;
    for (int base = beg + 64; base < end; base += 64) {
        int idx = base + lane;
        if (idx < end) {
            int s = esrc[idx];
            float e = a_s[s] + ad;
            e = (e > 0.f) ? e : 0.2f * e;
            m = fmaxf(m, e);
        }
    }
    #pragma unroll
    for (int off = 1; off < 64; off <<= 1) m = fmaxf(m, __shfl_xor(m, off));
    float ex0 = v0 ? expf(e0 - m) : 0.f;
    float den = ex0;
    for (int base = beg + 64; base < end; base += 64) {
        int idx = base + lane;
        if (idx < end) {
            int s = esrc[idx];
            float e = a_s[s] + ad;
            e = (e > 0.f) ? e : 0.2f * e;
            den += expf(e - m);
        }
    }
    #pragma unroll
    for (int off = 1; off < 64; off <<= 1) den += __shfl_xor(den, off);
    float rden = 1.f / den;

    float2 tg = {0.f, 0.f}, tc = {0.f, 0.f}, ts = {0.f, 0.f};
    int c = lane * 2;
    {
        float wg = ex0 * rden;      // 0 when invalid
        uint pw0 = (uint)f2b(wg) | ((uint)f2b(wc0) << 16);
        int cnt = end - beg; if (cnt > 64) cnt = 64;
        int j = 0;
        for (; j + 1 < cnt; j += 2) {
            int  sa  = __shfl(s0, j);
            uint pa  = __shfl(pw0, j);
            int  sb  = __shfl(s0, j + 1);
            uint pb  = __shfl(pw0, j + 1);
            ushort2 xa = *(const ushort2*)(xb + (size_t)sa * 128 + c);
            ushort2 xc = *(const ushort2*)(xb + (size_t)sb * 128 + c);
            float wga = b2f((ushort)(pa & 0xffffu)), wca = b2f((ushort)(pa >> 16));
            float ax = b2f(xa.x), ay = b2f(xa.y);
            tg.x += wga * ax; tg.y += wga * ay;
            tc.x += wca * ax; tc.y += wca * ay;
            ts.x += ax;       ts.y += ay;
            float wgb = b2f((ushort)(pb & 0xffffu)), wcb = b2f((ushort)(pb >> 16));
            float bx = b2f(xc.x), by = b2f(xc.y);
            tg.x += wgb * bx; tg.y += wgb * by;
            tc.x += wcb * bx; tc.y += wcb * by;
            ts.x += bx;       ts.y += by;
        }
        if (j < cnt) {
            int  sa = __shfl(s0, j);
            uint pa = __shfl(pw0, j);
            ushort2 xa = *(const ushort2*)(xb + (size_t)sa * 128 + c);
            float wga = b2f((ushort)(pa & 0xffffu)), wca = b2f((ushort)(pa >> 16));
            float ax = b2f(xa.x), ay = b2f(xa.y);
            tg.x += wga * ax; tg.y += wga * ay;
            tc.x += wca * ax; tc.y += wca * ay;
            ts.x += ax;       ts.y += ay;
        }
    }
    for (int base = beg + 64; base < end; base += 64) {
        int idx = base + lane;
        int s = d; uint pw = 0;
        if (idx < end) {
            s = esrc[idx];
            float e = a_s[s] + ad;
            e = (e > 0.f) ? e : 0.2f * e;
            float wg = expf(e - m) * rden;
            float wc = dinv[s] * dd;
            pw = (uint)f2b(wg) | ((uint)f2b(wc) << 16);
        }
        int cnt = end - base; if (cnt > 64) cnt = 64;
        int j = 0;
        for (; j + 1 < cnt; j += 2) {
            int  sa  = __shfl(s, j);
            uint pa  = __shfl(pw, j);
            int  sb  = __shfl(s, j + 1);
            uint pb  = __shfl(pw, j + 1);
            ushort2 xa = *(const ushort2*)(xb + (size_t)sa * 128 + c);
            ushort2 xc = *(const ushort2*)(xb + (size_t)sb * 128 + c);
            float wga = b2f((ushort)(pa & 0xffffu)), wca = b2f((ushort)(pa >> 16));
            float ax = b2f(xa.x), ay = b2f(xa.y);
            tg.x += wga * ax; tg.y += wga * ay;
            tc.x += wca * ax; tc.y += wca * ay;
            ts.x += ax;       ts.y += ay;
            float wgb = b2f((ushort)(pb & 0xffffu)), wcb = b2f((ushort)(pb >> 16));
            float bx = b2f(xc.x), by = b2f(xc.y);
            tg.x += wgb * bx; tg.y += wgb * by;
            tc.x += wcb * bx; tc.y += wcb * by;
            ts.x += bx;       ts.y += by;
        }
        if (j < cnt) {
            int  sa = __shfl(s, j);
            uint pa = __shfl(pw, j);
            ushort2 xa = *(const ushort2*)(xb + (size_t)sa * 128 + c);
            float wga = b2f((ushort)(pa & 0xffffu)), wca = b2f((ushort)(pa >> 16));
            float ax = b2f(xa.x), ay = b2f(xa.y);
            tg.x += wga * ax; tg.y += wga * ay;
            tc.x += wca * ax; tc.y += wca * ay;
            ts.x += ax;       ts.y += ay;
        }
    }
    ushort2 xdu = *(const ushort2*)(xb + (size_t)d * 128 + c);
    ts.x -= b2f(xdu.x); ts.y -= b2f(xdu.y);
    int cs = (end - beg) - 1;
    float rc = 1.f / (float)(cs > 1 ? cs : 1);
    ts.x *= rc; ts.y *= rc;

    size_t row = (size_t)d * 128 + c;
    { ushort2 u; u.x = f2b(tg.x); u.y = f2b(tg.y); *(ushort2*)(tgb + row) = u; }
    { ushort2 u; u.x = f2b(tc.x); u.y = f2b(tc.y); *(ushort2*)(tcb + row) = u; }
    { ushort2 u; u.x = f2b(ts.x); u.y = f2b(ts.y); *(ushort2*)(tsb + row) = u; }
}

// ---------- BN final: reduce per-block partials, fold gamma/beta ----------
__global__ void k_bn_final(const float* __restrict__ pS, const float* __restrict__ pQ,
                           const float* __restrict__ gamma, const float* __restrict__ beta,
                           float* __restrict__ scale, float* __restrict__ shift)
{
    int j = threadIdx.x;
    if (j >= C3) return;
    float s = 0.f, q = 0.f;
    for (int r = 0; r < NBLK; ++r) {
        s += pS[(size_t)r * C3 + j];
        q += pQ[(size_t)r * C3 + j];
    }
    const float rn = 1.f / (float)NN;
    float mu  = s * rn;
    float var = q * rn - mu * mu;
    float sc  = gamma[j] * rsqrtf(var + 1e-5f);
    scale[j] = sc;
    shift[j] = beta[j] - mu * sc;
}

// ---------- in-place BN+relu of hcat (8 elems/thread, 16B ld/st) ----------
__global__ __launch_bounds__(256) void k_bnrelu(
    ushort* __restrict__ hch,
    const float* __restrict__ scale, const float* __restrict__ shift)
{
    int p = blockIdx.x * blockDim.x + threadIdx.x;
    if (p >= NN * 48) return;
    int cidx = (p % 48) * 8;
    size_t o = (size_t)p * 8;
    uint4 w = *(uint4*)(hch + o);
    uint wr[4] = {w.x, w.y, w.z, w.w};
    uint out[4];
    #pragma unroll
    for (int i = 0; i < 4; ++i) {
        ushort u0 = (ushort)(wr[i] & 0xffffu), u1 = (ushort)(wr[i] >> 16);
        int cc = cidx + i * 2;
        float v0 = b2f(u0) * scale[cc]     + shift[cc];
        float v1 = b2f(u1) * scale[cc + 1] + shift[cc + 1];
        v0 = v0 > 0.f ? v0 : 0.f;
        v1 = v1 > 0.f ? v1 : 0.f;
        out[i] = (uint)f2b(v0) | ((uint)f2b(v1) << 16);
    }
    uint4 r; r.x = out[0]; r.y = out[1]; r.z = out[2]; r.w = out[3];
    *(uint4*)(hch + o) = r;
}

extern "C" void kernel_launch(void* const* d_in, const int* in_sizes, int n_in,
                              void* d_out, int out_size, void* d_ws, size_t ws_size,
                              hipStream_t stream) {
    const float* x        = (const float*)d_in[0];
    const int*   ei       = (const int*)d_in[1];
    const float* W_gat    = (const float*)d_in[2];
    const float* att_src  = (const float*)d_in[3];
    const float* att_dst  = (const float*)d_in[4];
    const float* b_gat    = (const float*)d_in[5];
    const float* W_gcn    = (const float*)d_in[6];
    const float* b_gcn    = (const float*)d_in[7];
    const float* W_sage_l = (const float*)d_in[8];
    const float* b_sage_l = (const float*)d_in[9];
    const float* W_sage_r = (const float*)d_in[10];
    const float* W1       = (const float*)d_in[11];
    const float* b1       = (const float*)d_in[12];
    const float* W2       = (const float*)d_in[13];
    const float* b2       = (const float*)d_in[14];
    const float* W3       = (const float*)d_in[15];
    const float* b3       = (const float*)d_in[16];
    const float* gamma    = (const float*)d_in[17];
    const float* beta     = (const float*)d_in[18];

    const int* e_src = ei;
    const int* e_dst = ei + EE;

    // ---- workspace layout (16B-aligned) ----
    char* base = (char*)d_ws;
    size_t o = 0;
    ushort* hch  = (ushort*)(base + o); o += (size_t)NN * C3 * 2;
    ushort* tgb  = (ushort*)(base + o); o += (size_t)NN * 128 * 2;    // a1 overlay
    ushort* tcb  = (ushort*)(base + o); o += (size_t)NN * 128 * 2;
    ushort* tsb  = (ushort*)(base + o); o += (size_t)NN * 128 * 2;    // a2 overlay
    ushort* xb   = (ushort*)(base + o); o += (size_t)NN * 128 * 2;
    ushort* esrc = (ushort*)(base + o); o += ((size_t)(EE + NN) * 2 + 15) & ~15ull;
    int*    offs = (int*)(base + o);    o += (size_t)(NN + 16) * 4;
    int*    cursor=(int*)(base + o);    o += (size_t)NN * 4;
    float*  as_  = (float*)(base + o);  o += (size_t)NN * 4;
    float*  ad_  = (float*)(base + o);  o += (size_t)NN * 4;
    float*  dinv = (float*)(base + o);  o += (size_t)NN * 4;
    int*    bsum = (int*)(base + o);    o += 256 * 4;
    int*    boffs= (int*)(base + o);    o += 256 * 4;
    // --- zero-init region: degA only ---
    int*    degA = (int*)(base + o);    o += (size_t)NN * 4;
    // --- end zero region ---
    float*  pS   = (float*)(base + o);  o += (size_t)NBLK * C3 * 4;   // written fully
    float*  pQ   = (float*)(base + o);  o += (size_t)NBLK * C3 * 4;
    float*  scale= (float*)(base + o);  o += C3 * 4;
    float*  shift= (float*)(base + o);  o += C3 * 4;
    float*  w_as = (float*)(base + o);  o += 128 * 4;
    float*  w_ad = (float*)(base + o);  o += 128 * 4;
    ushort* btg  = (ushort*)(base + o); o += 128 * 128 * 2;
    ushort* btc  = (ushort*)(base + o); o += 128 * 128 * 2;
    ushort* btsg = (ushort*)(base + o); o += 128 * 256 * 2;
    ushort* bt1  = (ushort*)(base + o); o += 256 * 384 * 2;
    ushort* bt2  = (ushort*)(base + o); o += 128 * 256 * 2;
    ushort* bt3  = (ushort*)(base + o); o += 48 * 128 * 2;
    // overlays (temporally disjoint)
    ushort* a1 = tgb;                        // NN*256 ushorts (tgb+tcb)
    ushort* a2 = tsb;                        // NN*128

    hipMemsetAsync(degA, 0, (size_t)NN * 4, stream);

    // ---- weight prep ----
    k_splitw_all<<<817, 256, 0, stream>>>(W_gat, W_gcn, W_sage_l, W_sage_r, W1, W2, W3,
        att_src, att_dst, w_as, w_ad, btg, btc, btsg, bt1, bt2, bt3);
    // split x + attention dots + degree histogram (merged)
    k_split_x_att<<<SPLIT_BLKS + HIST_BLKS, 256, 0, stream>>>(
        x, w_as, w_ad, e_dst, degA, xb, as_, ad_);

    // ---- CSR build ----
    k_scan_part<<<SC_BLKS, 256, 0, stream>>>(degA, bsum);
    k_scan_tops<<<1, 128, 0, stream>>>(bsum, boffs);
    k_scan_apply<<<SC_BLKS, 256, 0, stream>>>(degA, boffs, offs, cursor, dinv);
    k_csr_fill<<<(EE + NN + 255) / 256, 256, 0, stream>>>(e_src, e_dst, cursor, esrc);

    // ---- gather (bf16 x, ushort-src CSR, packed-weight shuffles, 2x unroll) ----
    k_gather<<<(NN + 3) / 4, 256, 0, stream>>>(
        esrc, offs, as_, ad_, dinv, xb, tgb, tcb, tsb);

    // ---- producers: one launch, privatized BN partials ----
    k_gemm_prod<<<dim3(NBLK, 1, 3), 256, 0, stream>>>(
        tgb, tcb, tsb, xb, btg, btc, btsg,
        b_gat, b_gcn, b_sage_l, pS, pQ, hch);

    // ---- BN fold (partials reduce) + standalone BN+relu pass ----
    k_bn_final<<<1, C3, 0, stream>>>(pS, pQ, gamma, beta, scale, shift);
    k_bnrelu<<<(NN * 48 + 255) / 256, 256, 0, stream>>>(hch, scale, shift);

    // ---- MLP ----
    k_gemm2<8, 3, 1><<<dim3(2, NBLK), 256, 0, stream>>>(
        hch, 384, bt1, NN, 0, b1, nullptr, 0, a1, 256, 256);
    k_gemm2<8, 2, 0><<<dim3(NBLK, 1), 256, 0, stream>>>(
        a1, 256, bt2, NN, 0, b2, nullptr, 0, a2, 128, 128);
    k_gemm2<3, 1, 0><<<dim3(NBLK, 1), 256, 0, stream>>>(
        a2, 128, bt3, NN, 2, b3, (float*)d_out, NOUT, nullptr, 0, NOUT);
}